// Round 10
// baseline (2752.435 us; speedup 1.0000x reference)
//
#include <hip/hip_runtime.h>
#include <hip/hip_bf16.h>

// Sizes
#define BB 16
#define NSEQ 20
#define HEADS 8
#define DH 96
#define DIM 768
#define FF 3072
#define KMEM 32768
#define NCHUNK 4
#define CHUNK 8192
#define NCH_OUT 16      // 4 chunks x 4 waves
#define TCAP 96
#define MARGIN 0.1f

typedef unsigned short u16;
typedef __attribute__((ext_vector_type(8))) short short8v;
typedef __attribute__((ext_vector_type(4))) float f32x4;
typedef __attribute__((ext_vector_type(16))) float f32x16;

__device__ __forceinline__ u16 f2bu(float x) {
    __hip_bfloat16 h = __float2bfloat16(x);
    return *reinterpret_cast<u16*>(&h);
}
__device__ __forceinline__ short f2bs(float x) {
    __hip_bfloat16 h = __float2bfloat16(x);
    return *reinterpret_cast<short*>(&h);
}

// ---------------------------------------------------------------- weight conversion
__global__ __launch_bounds__(256) void conv_k(const float* __restrict__ src, u16* __restrict__ dst, int n)
{
    int i = blockIdx.x * 256 + threadIdx.x;
    if (i < n) dst[i] = f2bu(src[i]);
}

__device__ __forceinline__ void tconv_tile(const float* __restrict__ src, u16* __restrict__ dst,
                                           int K, int N, int kt, int nt, int tx, int ty)
{
    __shared__ float tile[32][33];
    int k0 = kt * 32, n0 = nt * 32;
#pragma unroll
    for (int i = 0; i < 4; i++)
        tile[ty + 8 * i][tx] = src[(size_t)(k0 + ty + 8 * i) * N + n0 + tx];
    __syncthreads();
#pragma unroll
    for (int i = 0; i < 4; i++)
        dst[(size_t)(n0 + ty + 8 * i) * K + k0 + tx] = f2bu(tile[tx][ty + 8 * i]);
}

__global__ __launch_bounds__(256) void tconv_k(const float* __restrict__ src, u16* __restrict__ dst, int K, int N)
{
    int tilesN = N >> 5;
    tconv_tile(src, dst, K, N, blockIdx.x / tilesN, blockIdx.x % tilesN,
               threadIdx.x & 31, threadIdx.x >> 5);
}

__global__ __launch_bounds__(256) void wconv5L_k(const float* __restrict__ wq, const float* __restrict__ wkv,
    const float* __restrict__ wo, const float* __restrict__ w1, const float* __restrict__ w2,
    u16* __restrict__ wt, size_t wtStride)
{
    int l = blockIdx.y;
    wq += (size_t)l * 589824;
    wkv += (size_t)l * 147456;
    wo += (size_t)l * 589824;
    w1 += (size_t)l * 2359296;
    w2 += (size_t)l * 2359296;
    wt += (size_t)l * wtStride;
    int bx = blockIdx.x;
    int tx = threadIdx.x & 31, ty = threadIdx.x >> 5;
    if (bx < 576)       tconv_tile(wq,  wt + 0,       768, 768,  bx / 24,          bx % 24,          tx, ty);
    else if (bx < 720)  tconv_tile(wkv, wt + 589824,  768, 192,  (bx - 576) / 6,   (bx - 576) % 6,   tx, ty);
    else if (bx < 1296) tconv_tile(wo,  wt + 737280,  768, 768,  (bx - 720) / 24,  (bx - 720) % 24,  tx, ty);
    else if (bx < 3600) tconv_tile(w1,  wt + 1327104, 768, 3072, (bx - 1296) / 96, (bx - 1296) % 96, tx, ty);
    else                tconv_tile(w2,  wt + 3686400, 3072, 768, (bx - 3600) / 24, (bx - 3600) % 24, tx, ty);
}

// ---------------------------------------------------------------- MFMA GEMM, bf16 A[M][K] x Bt[N][K]
__device__ __forceinline__ void storeC(float* C, size_t idx, float v) { C[idx] = v; }
__device__ __forceinline__ void storeC(u16* C, size_t idx, float v)   { C[idx] = f2bu(v); }

template <typename CT>
__global__ __launch_bounds__(256) void gemm_bt(const u16* __restrict__ A, const u16* __restrict__ Bt,
    const float* __restrict__ bias, const float* __restrict__ resid, CT* __restrict__ C,
    int M, int N, int K, int lda, int ldc, float scale, int act)
{
    int tid = threadIdx.x;
    int w = tid >> 6, lane = tid & 63;
    int m0 = blockIdx.y * 16;
    int n0 = blockIdx.x * 128 + w * 32;
    int row = lane & 15;
    int kg  = lane >> 4;
    const u16* arow = A + (size_t)(m0 + row) * lda + kg * 8;
    int c0 = n0 + row;
    int c1 = n0 + 16 + row;
    const u16* bt0 = Bt + (size_t)min(c0, N - 1) * K + kg * 8;
    const u16* bt1 = Bt + (size_t)min(c1, N - 1) * K + kg * 8;
    f32x4 acc0 = {0.f, 0.f, 0.f, 0.f};
    f32x4 acc1 = {0.f, 0.f, 0.f, 0.f};
#pragma unroll 2
    for (int k0 = 0; k0 < K; k0 += 32) {
        short8v af = *(const short8v*)(arow + k0);
        short8v b0 = *(const short8v*)(bt0 + k0);
        short8v b1 = *(const short8v*)(bt1 + k0);
        acc0 = __builtin_amdgcn_mfma_f32_16x16x32_bf16(af, b0, acc0, 0, 0, 0);
        acc1 = __builtin_amdgcn_mfma_f32_16x16x32_bf16(af, b1, acc1, 0, 0, 0);
    }
#pragma unroll
    for (int r = 0; r < 4; r++) {
        int rw = m0 + kg * 4 + r;
        if (c0 < N) {
            float v = acc0[r] * scale;
            if (bias) v += bias[c0];
            if (act) {
                float xx = v;
                float tt = 0.7978845608028654f * (xx + 0.044715f * xx * xx * xx);
                v = 0.5f * xx * (1.0f + tanhf(tt));
            }
            if (resid) v += resid[(size_t)rw * ldc + c0];
            storeC(C, (size_t)rw * ldc + c0, v);
        }
        if (c1 < N) {
            float v = acc1[r] * scale;
            if (bias) v += bias[c1];
            if (act) {
                float xx = v;
                float tt = 0.7978845608028654f * (xx + 0.044715f * xx * xx * xx);
                v = 0.5f * xx * (1.0f + tanhf(tt));
            }
            if (resid) v += resid[(size_t)rw * ldc + c1];
            storeC(C, (size_t)rw * ldc + c1, v);
        }
    }
}

// Fused q+kv projection: Bt = [wq^T ; wkv^T] (960 rows, K=768).
__global__ __launch_bounds__(256) void gemm_qkv(const u16* __restrict__ A, const u16* __restrict__ Bt,
    float* __restrict__ qb, float* __restrict__ kvb, float qscale)
{
    const int N = 960, K = DIM;
    int tid = threadIdx.x;
    int w = tid >> 6, lane = tid & 63;
    int m0 = blockIdx.y * 16;
    int n0 = blockIdx.x * 128 + w * 32;
    int row = lane & 15;
    int kg  = lane >> 4;
    const u16* arow = A + (size_t)(m0 + row) * K + kg * 8;
    int c0 = n0 + row;
    int c1 = n0 + 16 + row;
    const u16* bt0 = Bt + (size_t)min(c0, N - 1) * K + kg * 8;
    const u16* bt1 = Bt + (size_t)min(c1, N - 1) * K + kg * 8;
    f32x4 acc0 = {0.f, 0.f, 0.f, 0.f};
    f32x4 acc1 = {0.f, 0.f, 0.f, 0.f};
#pragma unroll 2
    for (int k0 = 0; k0 < K; k0 += 32) {
        short8v af = *(const short8v*)(arow + k0);
        short8v b0 = *(const short8v*)(bt0 + k0);
        short8v b1 = *(const short8v*)(bt1 + k0);
        acc0 = __builtin_amdgcn_mfma_f32_16x16x32_bf16(af, b0, acc0, 0, 0, 0);
        acc1 = __builtin_amdgcn_mfma_f32_16x16x32_bf16(af, b1, acc1, 0, 0, 0);
    }
#pragma unroll
    for (int r = 0; r < 4; r++) {
        int rw = m0 + kg * 4 + r;
        if (c0 < 768)      qb[(size_t)rw * 768 + c0] = acc0[r] * qscale;
        else if (c0 < 960) kvb[(size_t)rw * 192 + (c0 - 768)] = acc0[r];
        if (c1 < 768)      qb[(size_t)rw * 768 + c1] = acc1[r] * qscale;
        else if (c1 < 960) kvb[(size_t)rw * 192 + (c1 - 768)] = acc1[r];
    }
}

// ---------------------------------------------------------------- LayerNorm (bf16 out)
__global__ __launch_bounds__(256) void ln_k(const float* __restrict__ x, const float* __restrict__ g,
    const float* __restrict__ bb, u16* __restrict__ y)
{
    int row = blockIdx.x;
    const float* xr = x + (size_t)row * DIM;
    int tid = threadIdx.x;
    float v0 = xr[tid], v1 = xr[tid + 256], v2 = xr[tid + 512];
    __shared__ float red[4];
    float s = v0 + v1 + v2;
    for (int off = 32; off; off >>= 1) s += __shfl_down(s, off);
    if ((tid & 63) == 0) red[tid >> 6] = s;
    __syncthreads();
    float mean = (red[0] + red[1] + red[2] + red[3]) * (1.f / 768.f);
    __syncthreads();
    float d0 = v0 - mean, d1 = v1 - mean, d2 = v2 - mean;
    s = d0 * d0 + d1 * d1 + d2 * d2;
    for (int off = 32; off; off >>= 1) s += __shfl_down(s, off);
    if ((tid & 63) == 0) red[tid >> 6] = s;
    __syncthreads();
    float var = (red[0] + red[1] + red[2] + red[3]) * (1.f / 768.f);
    float rs = rsqrtf(var + 1e-5f);
    u16* yr = y + (size_t)row * DIM;
    yr[tid]       = f2bu(d0 * rs * g[tid]       + bb[tid]);
    yr[tid + 256] = f2bu(d1 * rs * g[tid + 256] + bb[tid + 256]);
    yr[tid + 512] = f2bu(d2 * rs * g[tid + 512] + bb[tid + 512]);
}

// Final LN over rows i>=10, f32 output (16,10,768)
__global__ __launch_bounds__(256) void lnf_k(const float* __restrict__ x, const float* __restrict__ g,
    const float* __restrict__ bb, float* __restrict__ out)
{
    int blk = blockIdx.x;
    int b = blk / 10, ii = blk - b * 10;
    int row = b * NSEQ + 10 + ii;
    const float* xr = x + (size_t)row * DIM;
    int tid = threadIdx.x;
    float v0 = xr[tid], v1 = xr[tid + 256], v2 = xr[tid + 512];
    __shared__ float red[4];
    float s = v0 + v1 + v2;
    for (int off = 32; off; off >>= 1) s += __shfl_down(s, off);
    if ((tid & 63) == 0) red[tid >> 6] = s;
    __syncthreads();
    float mean = (red[0] + red[1] + red[2] + red[3]) * (1.f / 768.f);
    __syncthreads();
    float d0 = v0 - mean, d1 = v1 - mean, d2 = v2 - mean;
    s = d0 * d0 + d1 * d1 + d2 * d2;
    for (int off = 32; off; off >>= 1) s += __shfl_down(s, off);
    if ((tid & 63) == 0) red[tid >> 6] = s;
    __syncthreads();
    float var = (red[0] + red[1] + red[2] + red[3]) * (1.f / 768.f);
    float rs = rsqrtf(var + 1e-5f);
    float* orow = out + ((size_t)(b * 10 + ii)) * DIM;
    orow[tid]       = d0 * rs * g[tid]       + bb[tid];
    orow[tid + 256] = d1 * rs * g[tid + 256] + bb[tid + 256];
    orow[tid + 512] = d2 * rs * g[tid + 512] + bb[tid + 512];
}

// ---------------------------------------------------------------- prefix rows
__global__ __launch_bounds__(256) void prefix_k(const float* __restrict__ p, float* __restrict__ t)
{
    int idx = blockIdx.x * 256 + threadIdx.x;
    if (idx < BB * 7680) {
        int b = idx / 7680;
        int r = idx - b * 7680;
        t[(size_t)b * (NSEQ * DIM) + 7680 + r] = p[r];
    }
}

// ---------------------------------------------------------------- local attention (ao bf16)
__global__ __launch_bounds__(256) void lattn_k(const float* __restrict__ q, const float* __restrict__ kv,
    u16* __restrict__ ao)
{
    int b = blockIdx.x, h = blockIdx.y;
    __shared__ float sims[NSEQ][NSEQ];
    __shared__ float probs[NSEQ][NSEQ];
    const float* qb = q + (size_t)b * NSEQ * DIM + h * DH;
    const float* kb = kv + (size_t)b * NSEQ * 192;
    int tid = threadIdx.x;
    for (int p = tid; p < NSEQ * NSEQ; p += 256) {
        int i = p / NSEQ, j = p - i * NSEQ;
        float s;
        if (j > i) s = -1.0e9f;
        else {
            s = 0.f;
            for (int d = 0; d < DH; d++) s = fmaf(qb[(size_t)i * DIM + d], kb[j * 192 + d], s);
        }
        sims[i][j] = s;
    }
    __syncthreads();
    if (tid < NSEQ) {
        int i = tid;
        float m = -1e30f;
        for (int j = 0; j < NSEQ; j++) m = fmaxf(m, sims[i][j]);
        float sum = 0.f;
        for (int j = 0; j < NSEQ; j++) { float e = expf(sims[i][j] - m); probs[i][j] = e; sum += e; }
        float inv = 1.f / sum;
        for (int j = 0; j < NSEQ; j++) probs[i][j] *= inv;
    }
    __syncthreads();
    for (int p = tid; p < NSEQ * DH; p += 256) {
        int i = p / DH, d = p - i * DH;
        float o = 0.f;
        for (int j = 0; j <= i; j++) o = fmaf(probs[i][j], kb[j * 192 + 96 + d], o);
        ao[((size_t)b * NSEQ + i) * DIM + h * DH + d] = f2bu(o);
    }
}

// ---------------------------------------------------------------- top-k helpers
__device__ __forceinline__ bool tk_better(float va, int ia, float vb, int ib) {
    return (va > vb) || (va == vb && ia < ib);
}

__device__ __forceinline__ void lds_fence() {
    asm volatile("s_waitcnt lgkmcnt(0)" ::: "memory");
    __builtin_amdgcn_sched_barrier(0);
}

// Full bitonic sort of 128 elements (2 per lane) by (value desc, idx asc).
// After: v0 holds rank `lane`, v1 holds rank `lane+64`.
__device__ __forceinline__ void bitonic128(float& v0, int& i0, float& v1, int& i1, int lane)
{
#pragma unroll
    for (int k = 2; k <= 128; k <<= 1) {
#pragma unroll
        for (int j = 64; j >= 1; j >>= 1) {
            if (j >= k) continue;
            if (j == 64) {
                bool asc = ((lane & k) == 0);
                bool b01 = tk_better(v0, i0, v1, i1);
                if (b01 != asc) { float tv = v0; int ti = i0; v0 = v1; i0 = i1; v1 = tv; i1 = ti; }
            } else {
                {
                    float pv = __shfl_xor(v0, j); int pi = __shfl_xor(i0, j);
                    bool asc = ((lane & k) == 0);
                    bool first = ((lane & j) == 0);
                    bool mb = tk_better(v0, i0, pv, pi);
                    bool keep = first ? (mb == asc) : (mb != asc);
                    if (!keep) { v0 = pv; i0 = pi; }
                }
                {
                    float pv = __shfl_xor(v1, j); int pi = __shfl_xor(i1, j);
                    bool asc = (((lane + 64) & k) == 0);
                    bool first = ((lane & j) == 0);
                    bool mb = tk_better(v1, i1, pv, pi);
                    bool keep = first ? (mb == asc) : (mb != asc);
                    if (!keep) { v1 = pv; i1 = pi; }
                }
            }
        }
    }
}

// Exact top-32 of buf[0..cnt) by (value desc, idx asc).
__device__ void topk32(float* bv, int* bi, int cnt, int lane,
                       float& ov, int& oi) {
    lds_fence();
    float v0 = (lane < cnt)      ? bv[lane]      : -3.0e38f;
    int   i0 = (lane < cnt)      ? bi[lane]      : 0x7fffffff;
    float v1 = (lane + 64 < cnt) ? bv[lane + 64] : -3.0e38f;
    int   i1 = (lane + 64 < cnt) ? bi[lane + 64] : 0x7fffffff;
    lds_fence();
    bitonic128(v0, i0, v1, i1, lane);
    ov = v0; oi = i0;
}

// Sorted compaction: full sort, pivot = running approx rank-33 value (tightest
// valid), thr = max(thr, pivot - MARGIN), keep the (contiguous, sorted) prefix
// >= thr. Post-compaction cnt ~ 33 + margin-band => never overflows TCAP.
__device__ int sort_compact(float* bv, int* bi, int cnt, int lane, float& thr)
{
    lds_fence();
    float v0 = (lane < cnt)      ? bv[lane]      : -3.0e38f;
    int   i0 = (lane < cnt)      ? bi[lane]      : 0x7fffffff;
    float v1 = (lane + 64 < cnt) ? bv[lane + 64] : -3.0e38f;
    int   i1 = (lane + 64 < cnt) ? bi[lane + 64] : 0x7fffffff;
    lds_fence();
    bitonic128(v0, i0, v1, i1, lane);
    float pivot = __shfl(v0, 32);        // rank-33 (0-based rank 32)
    float nthr = pivot - MARGIN;
    if (nthr > thr) thr = nthr;
    int ncnt = __popcll(__ballot(v0 >= thr)) + __popcll(__ballot(v1 >= thr));
    bv[lane] = v0; bi[lane] = i0;
    if (lane + 64 < TCAP) { bv[lane + 64] = v1; bi[lane + 64] = i1; }
    lds_fence();
    return min(ncnt, TCAP);
}

// ---------------------------------------------------------------- mem top-k v5.1 (MFMA screen + exact recompute)
// Block (c,h,b); 4 waves each own a 2048-key window (subchunk = c*4+w).
// Approx sims via mfma_f32_32x32x16_bf16; margin-threshold retention (supersets
// exact top-32 for |approx-exact| <= MARGIN/2); exact f32 recompute; exact top-32.
__global__ __launch_bounds__(256, 2) void memtopk_k(const float* __restrict__ q, const float* __restrict__ memk,
    float* __restrict__ tkv, int* __restrict__ tki)
{
    __shared__ float bufv[4][NSEQ][TCAP];
    __shared__ int   bufi[4][NSEQ][TCAP];
    int c = blockIdx.x, h = blockIdx.y, b = blockIdx.z;
    int tid = threadIdx.x;
    int lane = tid & 63;
    int w = tid >> 6;
    int col = lane & 31;        // key-within-tile; also A-row (q row)
    int hi = lane >> 5;         // k-half selector

    // A fragments: 6 k-chunks of 16; lane holds q[col][ch*16 + hi*8 + j], rows >=20 zero
    short8v afrag[6];
    {
        const float* qr = q + ((size_t)(b * NSEQ + (col < NSEQ ? col : 0))) * DIM + h * DH;
#pragma unroll
        for (int ch = 0; ch < 6; ch++) {
            if (col < NSEQ) {
                float4 a0 = *(const float4*)(qr + ch * 16 + hi * 8);
                float4 a1 = *(const float4*)(qr + ch * 16 + hi * 8 + 4);
                afrag[ch][0] = f2bs(a0.x); afrag[ch][1] = f2bs(a0.y);
                afrag[ch][2] = f2bs(a0.z); afrag[ch][3] = f2bs(a0.w);
                afrag[ch][4] = f2bs(a1.x); afrag[ch][5] = f2bs(a1.y);
                afrag[ch][6] = f2bs(a1.z); afrag[ch][7] = f2bs(a1.w);
            } else {
#pragma unroll
                for (int j = 0; j < 8; j++) afrag[ch][j] = 0;
            }
        }
    }

    float thr[NSEQ]; int cnt[NSEQ];
#pragma unroll
    for (int r = 0; r < NSEQ; r++) { thr[r] = -3.0e38f; cnt[r] = 0; }

    const float* kbase = memk + (size_t)b * KMEM * DH;
    int k00 = c * CHUNK + w * 2048;

    for (int t = 0; t < 2048 / 32; t++) {
        int key0 = k00 + t * 32;
        const float* krow = kbase + (size_t)(key0 + col) * DH + hi * 8;
        f32x16 acc;
#pragma unroll
        for (int i = 0; i < 16; i++) acc[i] = 0.f;
#pragma unroll
        for (int ch = 0; ch < 6; ch++) {
            float4 p0 = *(const float4*)(krow + ch * 16);
            float4 p1 = *(const float4*)(krow + ch * 16 + 4);
            short8v bf;
            bf[0] = f2bs(p0.x); bf[1] = f2bs(p0.y); bf[2] = f2bs(p0.z); bf[3] = f2bs(p0.w);
            bf[4] = f2bs(p1.x); bf[5] = f2bs(p1.y); bf[6] = f2bs(p1.z); bf[7] = f2bs(p1.w);
            acc = __builtin_amdgcn_mfma_f32_32x32x16_bf16(afrag[ch], bf, acc, 0, 0, 0);
        }
        // row r lives in acc[(r&3)+4*(r>>3)] on lanes with hi == (r>>2)&1, col = key
#pragma unroll
        for (int r = 0; r < NSEQ; r++) {
            const int reg = (r & 3) + 4 * (r >> 3);
            const int rhi = (r >> 2) & 1;
            float a = acc[reg];
            bool cand = (hi == rhi) && (a >= thr[r]);
            unsigned long long mask = __ballot(cand);
            if (mask) {
                int n = __popcll(mask);
                if (cnt[r] + n > TCAP)
                    cnt[r] = sort_compact(&bufv[w][r][0], &bufi[w][r][0], cnt[r], lane, thr[r]);
                int pos = cnt[r] + __popcll(mask & ((1ull << lane) - 1ull));
                if (cand && pos < TCAP) { bufv[w][r][pos] = a; bufi[w][r][pos] = key0 + col; }
                cnt[r] = min(cnt[r] + n, TCAP);
            }
        }
    }

    // exact recompute + exact top-32 per row
    for (int r = 0; r < NSEQ; r++) {
        int cn = cnt[r];
        lds_fence();
        int idx0 = (lane < cn) ? bufi[w][r][lane] : 0;
        bool has1 = (lane < 32) && (lane + 64 < cn);
        int idx1 = has1 ? bufi[w][r][lane + 64] : 0;
        lds_fence();
        const float* qrow = q + ((size_t)(b * NSEQ + r)) * DIM + h * DH;
        const float* k0p = kbase + (size_t)idx0 * DH;
        const float* k1p = kbase + (size_t)idx1 * DH;
        float e0 = 0.f, e1 = 0.f;
        if (cn > 64) {
            for (int d4 = 0; d4 < 24; d4++) {
                float4 qv = *(const float4*)(qrow + d4 * 4);
                float4 ka = *(const float4*)(k0p + d4 * 4);
                float4 kb = *(const float4*)(k1p + d4 * 4);
                e0 = fmaf(qv.x, ka.x, e0); e0 = fmaf(qv.y, ka.y, e0);
                e0 = fmaf(qv.z, ka.z, e0); e0 = fmaf(qv.w, ka.w, e0);
                e1 = fmaf(qv.x, kb.x, e1); e1 = fmaf(qv.y, kb.y, e1);
                e1 = fmaf(qv.z, kb.z, e1); e1 = fmaf(qv.w, kb.w, e1);
            }
        } else {
            for (int d4 = 0; d4 < 24; d4++) {
                float4 qv = *(const float4*)(qrow + d4 * 4);
                float4 ka = *(const float4*)(k0p + d4 * 4);
                e0 = fmaf(qv.x, ka.x, e0); e0 = fmaf(qv.y, ka.y, e0);
                e0 = fmaf(qv.z, ka.z, e0); e0 = fmaf(qv.w, ka.w, e0);
            }
        }
        if (lane < cn) bufv[w][r][lane] = e0;
        if (has1) bufv[w][r][lane + 64] = e1;
        lds_fence();
        float ov; int oi;
        topk32(&bufv[w][r][0], &bufi[w][r][0], cn, lane, ov, oi);
        if (lane < 32) {
            size_t base = ((((size_t)b * HEADS + h) * NSEQ + r) * NCH_OUT + (c * 4 + w)) * 32;
            tkv[base + lane] = ov;
            tki[base + lane] = oi;
        }
    }
}

// ---------------------------------------------------------------- mem attention merge (per (i,h,b))
// Merges NCH_OUT*32 = 512 exact candidates -> exact top-32 -> softmax with local -> bf16 out.
__global__ __launch_bounds__(64) void memattn_k(const float* __restrict__ q, const float* __restrict__ kv,
    const float* __restrict__ memv, const float* __restrict__ tkv, const int* __restrict__ tki,
    u16* __restrict__ ao)
{
    int i = blockIdx.x, h = blockIdx.y, b = blockIdx.z;
    __shared__ float cv[NCH_OUT * 32];
    __shared__ int   ci[NCH_OUT * 32];
    __shared__ float selv[32];
    __shared__ int   seli[32];
    __shared__ float ls[NSEQ];
    __shared__ float probs[52];
    int tid = threadIdx.x;
    size_t base = (((size_t)b * HEADS + h) * NSEQ + i) * (NCH_OUT * 32);
#pragma unroll
    for (int s = 0; s < NCH_OUT * 32 / 64; s++) {
        cv[tid + 64 * s] = tkv[base + tid + 64 * s];
        ci[tid + 64 * s] = tki[base + tid + 64 * s];
    }
    const float* qr = q + ((size_t)b * NSEQ + i) * DIM + h * DH;
    const float* kvb = kv + (size_t)b * NSEQ * 192;
    if (tid <= i) {
        float s = 0.f;
        for (int d = 0; d < DH; d++) s = fmaf(qr[d], kvb[tid * 192 + d], s);
        ls[tid] = s;
    }
    __syncthreads();
    for (int r = 0; r < 32; r++) {
        float bv = -3.0e38f; int bidx = 0x7fffffff; int bs = 0;
#pragma unroll
        for (int s = 0; s < NCH_OUT * 32 / 64; s++) {
            float v = cv[tid + 64 * s]; int ix = ci[tid + 64 * s];
            if (tk_better(v, ix, bv, bidx)) { bv = v; bidx = ix; bs = tid + 64 * s; }
        }
        for (int off = 32; off; off >>= 1) {
            float ovv = __shfl_down(bv, off);
            int oii = __shfl_down(bidx, off);
            int oss = __shfl_down(bs, off);
            if (tk_better(ovv, oii, bv, bidx)) { bv = ovv; bidx = oii; bs = oss; }
        }
        if (tid == 0) { selv[r] = bv; seli[r] = bidx; cv[bs] = -3.0e38f; }
        __syncthreads();
    }
    if (tid == 0) {
        float m = -1e30f;
        for (int r = 0; r < 32; r++) m = fmaxf(m, selv[r]);
        for (int j = 0; j <= i; j++) m = fmaxf(m, ls[j]);
        float sum = 0.f;
        for (int r = 0; r < 32; r++) { float e = expf(selv[r] - m); probs[r] = e; sum += e; }
        for (int j = 0; j <= i; j++) { float e = expf(ls[j] - m); probs[32 + j] = e; sum += e; }
        float inv = 1.f / sum;
        for (int r = 0; r < 32 + i + 1; r++) probs[r] *= inv;
    }
    __syncthreads();
    const float* mvb = memv + (size_t)b * KMEM * DH;
    for (int d = tid; d < DH; d += 64) {
        float o = 0.f;
        for (int r = 0; r < 32; r++) o = fmaf(probs[r], mvb[(size_t)seli[r] * DH + d], o);
        for (int j = 0; j <= i; j++) o = fmaf(probs[32 + j], kvb[j * 192 + 96 + d], o);
        ao[((size_t)b * NSEQ + i) * DIM + h * DH + d] = f2bu(o);
    }
}

// ---------------------------------------------------------------- host
extern "C" void kernel_launch(void* const* d_in, const int* in_sizes, int n_in,
                              void* d_out, int out_size, void* d_ws, size_t ws_size,
                              hipStream_t stream) {
    const float* x            = (const float*)d_in[0];
    const float* linear_w     = (const float*)d_in[1];
    const float* linear_b     = (const float*)d_in[2];
    const float* prefix_const = (const float*)d_in[3];
    const float* ln1_g        = (const float*)d_in[4];
    const float* ln1_b        = (const float*)d_in[5];
    const float* wq           = (const float*)d_in[6];
    const float* wkv          = (const float*)d_in[7];
    const float* wo           = (const float*)d_in[8];
    const float* ln2_g        = (const float*)d_in[9];
    const float* ln2_b        = (const float*)d_in[10];
    const float* w1           = (const float*)d_in[11];
    const float* b1           = (const float*)d_in[12];
    const float* w2           = (const float*)d_in[13];
    const float* b2           = (const float*)d_in[14];
    const float* lnf_g        = (const float*)d_in[15];
    const float* lnf_b        = (const float*)d_in[16];
    const float* mem_k        = (const float*)d_in[17];
    const float* mem_v        = (const float*)d_in[18];

    float* ws = (float*)d_ws;
    float* t    = ws;                     // 320*768 f32
    u16*   yb   = (u16*)(ws + 245760);
    float* qb   = ws + 491520;
    float* kvb  = ws + 737280;
    u16*   aob  = (u16*)(ws + 798720);
    u16*   h1b  = (u16*)(ws + 1044480);
    float* tkv  = ws + 2027520;           // 16*8*20*16*32 = 1310720
    int*   tki  = (int*)(ws + 3338240);   // 1310720
    u16*   wt   = (u16*)(ws + 4648960);   // weight slots (bf16)
    float* out  = (float*)d_out;

    const size_t LAYER_WT = 6045696;      // shorts per layer slot
    const int all8 = (ws_size >= (size_t)(4648960 + 8 * 3022848 + 2560) * 4) ? 1 : 0;
    u16* xb = (u16*)(ws + (all8 ? (4648960 + 8 * 3022848) : (4648960 + 3022848)));

    const float qscale = 0.10206207261596577f; // 96^-0.5
    const size_t WOT = 737280, W1T = 1327104, W2T = 3686400;

    conv_k<<<40, 256, 0, stream>>>(x, xb, 16 * 640);
    tconv_k<<<4800, 256, 0, stream>>>(linear_w, wt, 640, 7680);
    gemm_bt<float><<<dim3(60, 1), 256, 0, stream>>>(xb, wt, linear_b, nullptr, t,
                                                    16, 7680, 640, 640, 15360, 1.f, 0);
    prefix_k<<<dim3(480), 256, 0, stream>>>(prefix_const, t);

    if (all8)
        wconv5L_k<<<dim3(5904, 8), 256, 0, stream>>>(wq, wkv, wo, w1, w2, wt, LAYER_WT);

    for (int l = 0; l < 8; l++) {
        u16* wtl = wt + (all8 ? (size_t)l * LAYER_WT : 0);
        if (!all8)
            wconv5L_k<<<dim3(5904, 1), 256, 0, stream>>>(wq + (size_t)l * 589824, wkv + (size_t)l * 147456,
                                                         wo + (size_t)l * 589824, w1 + (size_t)l * 2359296,
                                                         w2 + (size_t)l * 2359296, wtl, 0);
        ln_k<<<320, 256, 0, stream>>>(t, ln1_g + (size_t)l * DIM, ln1_b + (size_t)l * DIM, yb);
        gemm_qkv<<<dim3(8, 20), 256, 0, stream>>>(yb, wtl, qb, kvb, qscale);
        if (l == 4 || l == 5) {
            memtopk_k<<<dim3(NCHUNK, HEADS, BB), 256, 0, stream>>>(qb, mem_k, tkv, tki);
            memattn_k<<<dim3(NSEQ, HEADS, BB), 64, 0, stream>>>(qb, kvb, mem_v, tkv, tki, aob);
        } else {
            lattn_k<<<dim3(BB, HEADS), 256, 0, stream>>>(qb, kvb, aob);
        }
        gemm_bt<float><<<dim3(6, 20), 256, 0, stream>>>(aob, wtl + WOT, nullptr, t, t,
                                                        320, 768, 768, 768, 768, 1.f, 0);
        ln_k<<<320, 256, 0, stream>>>(t, ln2_g + (size_t)l * DIM, ln2_b + (size_t)l * DIM, yb);
        gemm_bt<u16><<<dim3(24, 20), 256, 0, stream>>>(yb, wtl + W1T, b1 + (size_t)l * FF, nullptr, h1b,
                                                       320, 3072, 768, 768, 3072, 1.f, 1);
        gemm_bt<float><<<dim3(6, 20), 256, 0, stream>>>(h1b, wtl + W2T, b2 + (size_t)l * DIM, t, t,
                                                        320, 768, 3072, 3072, 768, 1.f, 0);
    }
    lnf_k<<<160, 256, 0, stream>>>(t, lnf_g, lnf_b, out);
}

// Round 11
// 2097.357 us; speedup vs baseline: 1.3123x; 1.3123x over previous
//
#include <hip/hip_runtime.h>
#include <hip/hip_bf16.h>

// Sizes
#define BB 16
#define NSEQ 20
#define HEADS 8
#define DH 96
#define DIM 768
#define FF 3072
#define KMEM 32768
#define NCHUNK 4
#define CHUNK 8192
#define CAP 128

typedef unsigned short u16;
typedef __attribute__((ext_vector_type(8))) short short8v;
typedef __attribute__((ext_vector_type(4))) float f32x4;

__device__ __forceinline__ u16 f2bu(float x) {
    __hip_bfloat16 h = __float2bfloat16(x);
    return *reinterpret_cast<u16*>(&h);
}

// ---------------------------------------------------------------- weight conversion
__global__ __launch_bounds__(256) void conv_k(const float* __restrict__ src, u16* __restrict__ dst, int n)
{
    int i = blockIdx.x * 256 + threadIdx.x;
    if (i < n) dst[i] = f2bu(src[i]);
}

// transpose-convert one 32x32 tile: src[K][N] f32 -> dst[N][K] bf16 (dims % 32 == 0)
__device__ __forceinline__ void tconv_tile(const float* __restrict__ src, u16* __restrict__ dst,
                                           int K, int N, int kt, int nt, int tx, int ty)
{
    __shared__ float tile[32][33];
    int k0 = kt * 32, n0 = nt * 32;
#pragma unroll
    for (int i = 0; i < 4; i++)
        tile[ty + 8 * i][tx] = src[(size_t)(k0 + ty + 8 * i) * N + n0 + tx];
    __syncthreads();
#pragma unroll
    for (int i = 0; i < 4; i++)
        dst[(size_t)(n0 + ty + 8 * i) * K + k0 + tx] = f2bu(tile[tx][ty + 8 * i]);
}

__global__ __launch_bounds__(256) void tconv_k(const float* __restrict__ src, u16* __restrict__ dst, int K, int N)
{
    int tilesN = N >> 5;
    tconv_tile(src, dst, K, N, blockIdx.x / tilesN, blockIdx.x % tilesN,
               threadIdx.x & 31, threadIdx.x >> 5);
}

// all 5 weights of layer (blockIdx.y) in one launch; wtStride in shorts (0 => per-layer reuse)
__global__ __launch_bounds__(256) void wconv5L_k(const float* __restrict__ wq, const float* __restrict__ wkv,
    const float* __restrict__ wo, const float* __restrict__ w1, const float* __restrict__ w2,
    u16* __restrict__ wt, size_t wtStride)
{
    int l = blockIdx.y;
    wq += (size_t)l * 589824;
    wkv += (size_t)l * 147456;
    wo += (size_t)l * 589824;
    w1 += (size_t)l * 2359296;
    w2 += (size_t)l * 2359296;
    wt += (size_t)l * wtStride;
    int bx = blockIdx.x;
    int tx = threadIdx.x & 31, ty = threadIdx.x >> 5;
    if (bx < 576)       tconv_tile(wq,  wt + 0,       768, 768,  bx / 24,          bx % 24,          tx, ty);
    else if (bx < 720)  tconv_tile(wkv, wt + 589824,  768, 192,  (bx - 576) / 6,   (bx - 576) % 6,   tx, ty);
    else if (bx < 1296) tconv_tile(wo,  wt + 737280,  768, 768,  (bx - 720) / 24,  (bx - 720) % 24,  tx, ty);
    else if (bx < 3600) tconv_tile(w1,  wt + 1327104, 768, 3072, (bx - 1296) / 96, (bx - 1296) % 96, tx, ty);
    else                tconv_tile(w2,  wt + 3686400, 3072, 768, (bx - 3600) / 24, (bx - 3600) % 24, tx, ty);
}

// ---------------------------------------------------------------- MFMA GEMM, bf16 A[M][K] x Bt[N][K]
__device__ __forceinline__ void storeC(float* C, size_t idx, float v) { C[idx] = v; }
__device__ __forceinline__ void storeC(u16* C, size_t idx, float v)   { C[idx] = f2bu(v); }

template <typename CT>
__global__ __launch_bounds__(256) void gemm_bt(const u16* __restrict__ A, const u16* __restrict__ Bt,
    const float* __restrict__ bias, const float* __restrict__ resid, CT* __restrict__ C,
    int M, int N, int K, int lda, int ldc, float scale, int act)
{
    int tid = threadIdx.x;
    int w = tid >> 6, lane = tid & 63;
    int m0 = blockIdx.y * 16;
    int n0 = blockIdx.x * 128 + w * 32;
    int row = lane & 15;
    int kg  = lane >> 4;
    const u16* arow = A + (size_t)(m0 + row) * lda + kg * 8;
    int c0 = n0 + row;
    int c1 = n0 + 16 + row;
    const u16* bt0 = Bt + (size_t)min(c0, N - 1) * K + kg * 8;
    const u16* bt1 = Bt + (size_t)min(c1, N - 1) * K + kg * 8;
    f32x4 acc0 = {0.f, 0.f, 0.f, 0.f};
    f32x4 acc1 = {0.f, 0.f, 0.f, 0.f};
#pragma unroll 4
    for (int k0 = 0; k0 < K; k0 += 32) {
        short8v af = *(const short8v*)(arow + k0);
        short8v b0 = *(const short8v*)(bt0 + k0);
        short8v b1 = *(const short8v*)(bt1 + k0);
        acc0 = __builtin_amdgcn_mfma_f32_16x16x32_bf16(af, b0, acc0, 0, 0, 0);
        acc1 = __builtin_amdgcn_mfma_f32_16x16x32_bf16(af, b1, acc1, 0, 0, 0);
    }
#pragma unroll
    for (int r = 0; r < 4; r++) {
        int rw = m0 + kg * 4 + r;
        if (c0 < N) {
            float v = acc0[r] * scale;
            if (bias) v += bias[c0];
            if (act) {
                float xx = v;
                float tt = 0.7978845608028654f * (xx + 0.044715f * xx * xx * xx);
                v = 0.5f * xx * (1.0f + tanhf(tt));
            }
            if (resid) v += resid[(size_t)rw * ldc + c0];
            storeC(C, (size_t)rw * ldc + c0, v);
        }
        if (c1 < N) {
            float v = acc1[r] * scale;
            if (bias) v += bias[c1];
            if (act) {
                float xx = v;
                float tt = 0.7978845608028654f * (xx + 0.044715f * xx * xx * xx);
                v = 0.5f * xx * (1.0f + tanhf(tt));
            }
            if (resid) v += resid[(size_t)rw * ldc + c1];
            storeC(C, (size_t)rw * ldc + c1, v);
        }
    }
}

// Fused q+kv projection: Bt = [wq^T ; wkv^T] (960 rows, K=768).
// cols 0..767 -> qb (*qscale, ld 768); cols 768..959 -> kvb (ld 192).
__global__ __launch_bounds__(256) void gemm_qkv(const u16* __restrict__ A, const u16* __restrict__ Bt,
    float* __restrict__ qb, float* __restrict__ kvb, float qscale)
{
    const int N = 960, K = DIM;
    int tid = threadIdx.x;
    int w = tid >> 6, lane = tid & 63;
    int m0 = blockIdx.y * 16;
    int n0 = blockIdx.x * 128 + w * 32;
    int row = lane & 15;
    int kg  = lane >> 4;
    const u16* arow = A + (size_t)(m0 + row) * K + kg * 8;
    int c0 = n0 + row;
    int c1 = n0 + 16 + row;
    const u16* bt0 = Bt + (size_t)min(c0, N - 1) * K + kg * 8;
    const u16* bt1 = Bt + (size_t)min(c1, N - 1) * K + kg * 8;
    f32x4 acc0 = {0.f, 0.f, 0.f, 0.f};
    f32x4 acc1 = {0.f, 0.f, 0.f, 0.f};
#pragma unroll 4
    for (int k0 = 0; k0 < K; k0 += 32) {
        short8v af = *(const short8v*)(arow + k0);
        short8v b0 = *(const short8v*)(bt0 + k0);
        short8v b1 = *(const short8v*)(bt1 + k0);
        acc0 = __builtin_amdgcn_mfma_f32_16x16x32_bf16(af, b0, acc0, 0, 0, 0);
        acc1 = __builtin_amdgcn_mfma_f32_16x16x32_bf16(af, b1, acc1, 0, 0, 0);
    }
#pragma unroll
    for (int r = 0; r < 4; r++) {
        int rw = m0 + kg * 4 + r;
        if (c0 < 768)      qb[(size_t)rw * 768 + c0] = acc0[r] * qscale;
        else if (c0 < 960) kvb[(size_t)rw * 192 + (c0 - 768)] = acc0[r];
        if (c1 < 768)      qb[(size_t)rw * 768 + c1] = acc1[r] * qscale;
        else if (c1 < 960) kvb[(size_t)rw * 192 + (c1 - 768)] = acc1[r];
    }
}

// ---------------------------------------------------------------- LayerNorm (bf16 out)
__global__ __launch_bounds__(256) void ln_k(const float* __restrict__ x, const float* __restrict__ g,
    const float* __restrict__ bb, u16* __restrict__ y)
{
    int row = blockIdx.x;
    const float* xr = x + (size_t)row * DIM;
    int tid = threadIdx.x;
    float v0 = xr[tid], v1 = xr[tid + 256], v2 = xr[tid + 512];
    __shared__ float red[4];
    float s = v0 + v1 + v2;
    for (int off = 32; off; off >>= 1) s += __shfl_down(s, off);
    if ((tid & 63) == 0) red[tid >> 6] = s;
    __syncthreads();
    float mean = (red[0] + red[1] + red[2] + red[3]) * (1.f / 768.f);
    __syncthreads();
    float d0 = v0 - mean, d1 = v1 - mean, d2 = v2 - mean;
    s = d0 * d0 + d1 * d1 + d2 * d2;
    for (int off = 32; off; off >>= 1) s += __shfl_down(s, off);
    if ((tid & 63) == 0) red[tid >> 6] = s;
    __syncthreads();
    float var = (red[0] + red[1] + red[2] + red[3]) * (1.f / 768.f);
    float rs = rsqrtf(var + 1e-5f);
    u16* yr = y + (size_t)row * DIM;
    yr[tid]       = f2bu(d0 * rs * g[tid]       + bb[tid]);
    yr[tid + 256] = f2bu(d1 * rs * g[tid + 256] + bb[tid + 256]);
    yr[tid + 512] = f2bu(d2 * rs * g[tid + 512] + bb[tid + 512]);
}

// Final LN over rows i>=10, f32 output (16,10,768)
__global__ __launch_bounds__(256) void lnf_k(const float* __restrict__ x, const float* __restrict__ g,
    const float* __restrict__ bb, float* __restrict__ out)
{
    int blk = blockIdx.x;
    int b = blk / 10, ii = blk - b * 10;
    int row = b * NSEQ + 10 + ii;
    const float* xr = x + (size_t)row * DIM;
    int tid = threadIdx.x;
    float v0 = xr[tid], v1 = xr[tid + 256], v2 = xr[tid + 512];
    __shared__ float red[4];
    float s = v0 + v1 + v2;
    for (int off = 32; off; off >>= 1) s += __shfl_down(s, off);
    if ((tid & 63) == 0) red[tid >> 6] = s;
    __syncthreads();
    float mean = (red[0] + red[1] + red[2] + red[3]) * (1.f / 768.f);
    __syncthreads();
    float d0 = v0 - mean, d1 = v1 - mean, d2 = v2 - mean;
    s = d0 * d0 + d1 * d1 + d2 * d2;
    for (int off = 32; off; off >>= 1) s += __shfl_down(s, off);
    if ((tid & 63) == 0) red[tid >> 6] = s;
    __syncthreads();
    float var = (red[0] + red[1] + red[2] + red[3]) * (1.f / 768.f);
    float rs = rsqrtf(var + 1e-5f);
    float* orow = out + ((size_t)(b * 10 + ii)) * DIM;
    orow[tid]       = d0 * rs * g[tid]       + bb[tid];
    orow[tid + 256] = d1 * rs * g[tid + 256] + bb[tid + 256];
    orow[tid + 512] = d2 * rs * g[tid + 512] + bb[tid + 512];
}

// ---------------------------------------------------------------- prefix rows
__global__ __launch_bounds__(256) void prefix_k(const float* __restrict__ p, float* __restrict__ t)
{
    int idx = blockIdx.x * 256 + threadIdx.x;
    if (idx < BB * 7680) {
        int b = idx / 7680;
        int r = idx - b * 7680;
        t[(size_t)b * (NSEQ * DIM) + 7680 + r] = p[r];
    }
}

// ---------------------------------------------------------------- local attention (ao bf16)
// float4 dots in sequential accumulation order (bit-identical to scalar loop).
__device__ __forceinline__ float dot96(const float* __restrict__ a, const float* __restrict__ b)
{
    float s = 0.f;
#pragma unroll
    for (int d4 = 0; d4 < 24; d4++) {
        float4 av = *(const float4*)(a + d4 * 4);
        float4 bv = *(const float4*)(b + d4 * 4);
        s = fmaf(av.x, bv.x, s);
        s = fmaf(av.y, bv.y, s);
        s = fmaf(av.z, bv.z, s);
        s = fmaf(av.w, bv.w, s);
    }
    return s;
}

__global__ __launch_bounds__(256) void lattn_k(const float* __restrict__ q, const float* __restrict__ kv,
    u16* __restrict__ ao)
{
    int b = blockIdx.x, h = blockIdx.y;
    __shared__ float sims[NSEQ][NSEQ];
    __shared__ float probs[NSEQ][NSEQ];
    const float* qb = q + (size_t)b * NSEQ * DIM + h * DH;
    const float* kb = kv + (size_t)b * NSEQ * 192;
    int tid = threadIdx.x;
    for (int p = tid; p < NSEQ * NSEQ; p += 256) {
        int i = p / NSEQ, j = p - i * NSEQ;
        float s;
        if (j > i) s = -1.0e9f;
        else s = dot96(qb + (size_t)i * DIM, kb + j * 192);
        sims[i][j] = s;
    }
    __syncthreads();
    if (tid < NSEQ) {
        int i = tid;
        float m = -1e30f;
        for (int j = 0; j < NSEQ; j++) m = fmaxf(m, sims[i][j]);
        float sum = 0.f;
        for (int j = 0; j < NSEQ; j++) { float e = expf(sims[i][j] - m); probs[i][j] = e; sum += e; }
        float inv = 1.f / sum;
        for (int j = 0; j < NSEQ; j++) probs[i][j] *= inv;
    }
    __syncthreads();
    for (int p = tid; p < NSEQ * DH; p += 256) {
        int i = p / DH, d = p - i * DH;
        float o = 0.f;
        for (int j = 0; j <= i; j++) o = fmaf(probs[i][j], kb[j * 192 + 96 + d], o);
        ao[((size_t)b * NSEQ + i) * DIM + h * DH + d] = f2bu(o);
    }
}

// ---------------------------------------------------------------- top-k helpers
__device__ __forceinline__ bool tk_better(float va, int ia, float vb, int ib) {
    return (va > vb) || (va == vb && ia < ib);
}

__device__ __forceinline__ void lds_fence() {
    asm volatile("s_waitcnt lgkmcnt(0)" ::: "memory");
    __builtin_amdgcn_sched_barrier(0);
}

// Exact top-32 of buf[0..cnt) by (value desc, idx asc). Bitonic-128 in regs.
__device__ void topk32(float* bv, int* bi, int cnt, int lane,
                       float& ov, int& oi, float& thr_out) {
    lds_fence();
    float v0 = (lane < cnt)      ? bv[lane]      : -3.0e38f;
    int   i0 = (lane < cnt)      ? bi[lane]      : 0x7fffffff;
    float v1 = (lane + 64 < cnt) ? bv[lane + 64] : -3.0e38f;
    int   i1 = (lane + 64 < cnt) ? bi[lane + 64] : 0x7fffffff;
    lds_fence();
#pragma unroll
    for (int k = 2; k <= 128; k <<= 1) {
#pragma unroll
        for (int j = 64; j >= 1; j >>= 1) {
            if (j >= k) continue;
            if (j == 64) {
                bool asc = ((lane & k) == 0);
                bool b01 = tk_better(v0, i0, v1, i1);
                if (b01 != asc) { float tv = v0; int ti = i0; v0 = v1; i0 = i1; v1 = tv; i1 = ti; }
            } else {
                {
                    float pv = __shfl_xor(v0, j); int pi = __shfl_xor(i0, j);
                    bool asc = ((lane & k) == 0);
                    bool first = ((lane & j) == 0);
                    bool mb = tk_better(v0, i0, pv, pi);
                    bool keep = first ? (mb == asc) : (mb != asc);
                    if (!keep) { v0 = pv; i0 = pi; }
                }
                {
                    float pv = __shfl_xor(v1, j); int pi = __shfl_xor(i1, j);
                    bool asc = (((lane + 64) & k) == 0);
                    bool first = ((lane & j) == 0);
                    bool mb = tk_better(v1, i1, pv, pi);
                    bool keep = first ? (mb == asc) : (mb != asc);
                    if (!keep) { v1 = pv; i1 = pi; }
                }
            }
        }
    }
    if (lane < 32) { bv[lane] = v0; bi[lane] = i0; }
    lds_fence();
    ov = v0; oi = i0;
    thr_out = __shfl(v0, 31);
}

// One 16-key pass: dot (quarter-split), 4-lane reduce, threshold/ballot append.
__device__ __forceinline__ void tk_pass(const float4 kr[6], const float4 qreg[5][6],
    float thrR[5], int cntR[5], float (*bufv)[CAP], int (*bufi)[CAP],
    int r0, int lane, int qt, int key)
{
    float a[5];
#pragma unroll
    for (int rr = 0; rr < 5; rr++) a[rr] = 0.f;
#pragma unroll
    for (int i = 0; i < 6; i++) {
        float4 kv = kr[i];
#pragma unroll
        for (int rr = 0; rr < 5; rr++) {
            float4 qv = qreg[rr][i];
            a[rr] = fmaf(qv.x, kv.x, a[rr]);
            a[rr] = fmaf(qv.y, kv.y, a[rr]);
            a[rr] = fmaf(qv.z, kv.z, a[rr]);
            a[rr] = fmaf(qv.w, kv.w, a[rr]);
        }
    }
#pragma unroll
    for (int rr = 0; rr < 5; rr++) {
        a[rr] += __shfl_xor(a[rr], 1);
        a[rr] += __shfl_xor(a[rr], 2);
    }
#pragma unroll
    for (int rr = 0; rr < 5; rr++) {
        bool cand = (qt == 0) && (a[rr] >= thrR[rr]);
        unsigned long long mask = __ballot(cand);
        int n = __popcll(mask);
        if (n) {
            int r = r0 + rr;
            if (cntR[rr] + n > CAP) {
                float dv; int di;
                topk32(&bufv[r][0], &bufi[r][0], cntR[rr], lane, dv, di, thrR[rr]);
                cntR[rr] = 32;
            }
            int pos = cntR[rr] + __popcll(mask & ((1ull << lane) - 1ull));
            if (cand) { bufv[r][pos] = a[rr]; bufi[r][pos] = key; }
            cntR[rr] += n;
        }
    }
}

// ---------------------------------------------------------------- mem top-k (v4, measured-best)
// Block (c,h,b), 256 thr = 4 waves; wave w owns rows 5w..5w+4. Q in regs,
// k double-buffered in regs. 512 blocks.
__global__ __launch_bounds__(256, 2) void memtopk_k(const float* __restrict__ q, const float* __restrict__ memk,
    float* __restrict__ tkv, int* __restrict__ tki)
{
    __shared__ float bufv[NSEQ][CAP];
    __shared__ int   bufi[NSEQ][CAP];
    int c = blockIdx.x, h = blockIdx.y, b = blockIdx.z;
    int tid = threadIdx.x;
    int lane = tid & 63;
    int w = tid >> 6;
    int r0 = w * 5;
    int qt = lane & 3;
    int kk = lane >> 2;

    float4 qreg[5][6];
#pragma unroll
    for (int rr = 0; rr < 5; rr++) {
        const float4* qrow = (const float4*)(q + ((size_t)(b * NSEQ + r0 + rr)) * DIM + h * DH + qt * 24);
#pragma unroll
        for (int i = 0; i < 6; i++) qreg[rr][i] = qrow[i];
    }

    float thrR[5]; int cntR[5];
#pragma unroll
    for (int rr = 0; rr < 5; rr++) { thrR[rr] = -3.0e38f; cntR[rr] = 0; }

    const float* kbase = memk + (size_t)b * KMEM * DH;
    int k0 = c * CHUNK;

    float4 ka[6], kb2[6];
    {
        const float4* kp = (const float4*)(kbase + (size_t)(k0 + kk) * DH + qt * 24);
#pragma unroll
        for (int i = 0; i < 6; i++) ka[i] = kp[i];
    }
    for (int p = 0; p < CHUNK / 16; p += 2) {
        int key0 = k0 + p * 16 + kk;
        {
            const float4* kp = (const float4*)(kbase + (size_t)(key0 + 16) * DH + qt * 24);
#pragma unroll
            for (int i = 0; i < 6; i++) kb2[i] = kp[i];
        }
        tk_pass(ka, qreg, thrR, cntR, bufv, bufi, r0, lane, qt, key0);
        if (p + 2 < CHUNK / 16) {
            const float4* kp = (const float4*)(kbase + (size_t)(key0 + 32) * DH + qt * 24);
#pragma unroll
            for (int i = 0; i < 6; i++) ka[i] = kp[i];
        }
        tk_pass(kb2, qreg, thrR, cntR, bufv, bufi, r0, lane, qt, key0 + 16);
    }
#pragma unroll
    for (int rr = 0; rr < 5; rr++) {
        int r = r0 + rr;
        float ov; int oi; float dthr;
        topk32(&bufv[r][0], &bufi[r][0], cntR[rr], lane, ov, oi, dthr);
        if (lane < 32) {
            size_t base = ((((size_t)b * HEADS + h) * NSEQ + r) * NCHUNK + c) * 32;
            tkv[base + lane] = ov;
            tki[base + lane] = oi;
        }
    }
}

// ---------------------------------------------------------------- mem attention merge (per (i,h,b))
__global__ __launch_bounds__(64) void memattn_k(const float* __restrict__ q, const float* __restrict__ kv,
    const float* __restrict__ memv, const float* __restrict__ tkv, const int* __restrict__ tki,
    u16* __restrict__ ao)
{
    int i = blockIdx.x, h = blockIdx.y, b = blockIdx.z;
    __shared__ float cv[NCHUNK * 32];
    __shared__ int   ci[NCHUNK * 32];
    __shared__ float selv[32];
    __shared__ int   seli[32];
    __shared__ float ls[NSEQ];
    __shared__ float probs[52];
    int tid = threadIdx.x;
    size_t base = (((size_t)b * HEADS + h) * NSEQ + i) * (NCHUNK * 32);
#pragma unroll
    for (int s = 0; s < NCHUNK * 32 / 64; s++) {
        cv[tid + 64 * s] = tkv[base + tid + 64 * s];
        ci[tid + 64 * s] = tki[base + tid + 64 * s];
    }
    const float* qr = q + ((size_t)b * NSEQ + i) * DIM + h * DH;
    const float* kvb = kv + (size_t)b * NSEQ * 192;
    if (tid <= i) {
        float s = dot96(qr, kvb + tid * 192);
        ls[tid] = s;
    }
    __syncthreads();
    for (int r = 0; r < 32; r++) {
        float bv = -3.0e38f; int bidx = 0x7fffffff; int bs = 0;
#pragma unroll
        for (int s = 0; s < NCHUNK * 32 / 64; s++) {
            float v = cv[tid + 64 * s]; int ix = ci[tid + 64 * s];
            if (tk_better(v, ix, bv, bidx)) { bv = v; bidx = ix; bs = tid + 64 * s; }
        }
        for (int off = 32; off; off >>= 1) {
            float ovv = __shfl_down(bv, off);
            int oii = __shfl_down(bidx, off);
            int oss = __shfl_down(bs, off);
            if (tk_better(ovv, oii, bv, bidx)) { bv = ovv; bidx = oii; bs = oss; }
        }
        if (tid == 0) { selv[r] = bv; seli[r] = bidx; cv[bs] = -3.0e38f; }
        __syncthreads();
    }
    if (tid == 0) {
        float m = -1e30f;
        for (int r = 0; r < 32; r++) m = fmaxf(m, selv[r]);
        for (int j = 0; j <= i; j++) m = fmaxf(m, ls[j]);
        float sum = 0.f;
        for (int r = 0; r < 32; r++) { float e = expf(selv[r] - m); probs[r] = e; sum += e; }
        for (int j = 0; j <= i; j++) { float e = expf(ls[j] - m); probs[32 + j] = e; sum += e; }
        float inv = 1.f / sum;
        for (int r = 0; r < 32 + i + 1; r++) probs[r] *= inv;
    }
    __syncthreads();
    const float* mvb = memv + (size_t)b * KMEM * DH;
    for (int d = tid; d < DH; d += 64) {
        float o = 0.f;
        for (int r = 0; r < 32; r++) o = fmaf(probs[r], mvb[(size_t)seli[r] * DH + d], o);
        for (int j = 0; j <= i; j++) o = fmaf(probs[32 + j], kvb[j * 192 + 96 + d], o);
        ao[((size_t)b * NSEQ + i) * DIM + h * DH + d] = f2bu(o);
    }
}

// ---------------------------------------------------------------- host
extern "C" void kernel_launch(void* const* d_in, const int* in_sizes, int n_in,
                              void* d_out, int out_size, void* d_ws, size_t ws_size,
                              hipStream_t stream) {
    const float* x            = (const float*)d_in[0];
    const float* linear_w     = (const float*)d_in[1];
    const float* linear_b     = (const float*)d_in[2];
    const float* prefix_const = (const float*)d_in[3];
    const float* ln1_g        = (const float*)d_in[4];
    const float* ln1_b        = (const float*)d_in[5];
    const float* wq           = (const float*)d_in[6];
    const float* wkv          = (const float*)d_in[7];
    const float* wo           = (const float*)d_in[8];
    const float* ln2_g        = (const float*)d_in[9];
    const float* ln2_b        = (const float*)d_in[10];
    const float* w1           = (const float*)d_in[11];
    const float* b1           = (const float*)d_in[12];
    const float* w2           = (const float*)d_in[13];
    const float* b2           = (const float*)d_in[14];
    const float* lnf_g        = (const float*)d_in[15];
    const float* lnf_b        = (const float*)d_in[16];
    const float* mem_k        = (const float*)d_in[17];
    const float* mem_v        = (const float*)d_in[18];

    float* ws = (float*)d_ws;
    float* t    = ws;                     // 320*768 f32
    u16*   yb   = (u16*)(ws + 245760);    // 320*768 bf16
    float* qb   = ws + 491520;            // 320*768 f32
    float* kvb  = ws + 737280;            // 320*192 f32
    u16*   aob  = (u16*)(ws + 798720);    // 320*768 bf16
    u16*   h1b  = (u16*)(ws + 1044480);   // 320*3072 bf16
    float* tkv  = ws + 2027520;           // 16*8*20*4*32 = 327680
    int*   tki  = (int*)(ws + 2355200);   // 327680
    u16*   wt   = (u16*)(ws + 2682880);   // weight slots (bf16)
    float* out  = (float*)d_out;

    const size_t LAYER_WT = 6045696;      // shorts per layer slot
    const int all8 = (ws_size >= (size_t)(2682880 + 8 * 3022848 + 2560) * 4) ? 1 : 0;
    u16* xb = (u16*)(ws + (all8 ? (2682880 + 8 * 3022848) : (2682880 + 3022848)));

    const float qscale = 0.10206207261596577f; // 96^-0.5
    const size_t WOT = 737280, W1T = 1327104, W2T = 3686400;

    conv_k<<<40, 256, 0, stream>>>(x, xb, 16 * 640);
    tconv_k<<<4800, 256, 0, stream>>>(linear_w, wt, 640, 7680);
    gemm_bt<float><<<dim3(60, 1), 256, 0, stream>>>(xb, wt, linear_b, nullptr, t,
                                                    16, 7680, 640, 640, 15360, 1.f, 0);
    prefix_k<<<dim3(480), 256, 0, stream>>>(prefix_const, t);

    if (all8)
        wconv5L_k<<<dim3(5904, 8), 256, 0, stream>>>(wq, wkv, wo, w1, w2, wt, LAYER_WT);

    for (int l = 0; l < 8; l++) {
        u16* wtl = wt + (all8 ? (size_t)l * LAYER_WT : 0);
        if (!all8)
            wconv5L_k<<<dim3(5904, 1), 256, 0, stream>>>(wq + (size_t)l * 589824, wkv + (size_t)l * 147456,
                                                         wo + (size_t)l * 589824, w1 + (size_t)l * 2359296,
                                                         w2 + (size_t)l * 2359296, wtl, 0);
        ln_k<<<320, 256, 0, stream>>>(t, ln1_g + (size_t)l * DIM, ln1_b + (size_t)l * DIM, yb);
        gemm_qkv<<<dim3(8, 20), 256, 0, stream>>>(yb, wtl, qb, kvb, qscale);
        if (l == 4 || l == 5) {
            memtopk_k<<<dim3(NCHUNK, HEADS, BB), 256, 0, stream>>>(qb, mem_k, tkv, tki);
            memattn_k<<<dim3(NSEQ, HEADS, BB), 64, 0, stream>>>(qb, kvb, mem_v, tkv, tki, aob);
        } else {
            lattn_k<<<dim3(BB, HEADS), 256, 0, stream>>>(qb, kvb, aob);
        }
        gemm_bt<float><<<dim3(6, 20), 256, 0, stream>>>(aob, wtl + WOT, nullptr, t, t,
                                                        320, 768, 768, 768, 768, 1.f, 0);
        ln_k<<<320, 256, 0, stream>>>(t, ln2_g + (size_t)l * DIM, ln2_b + (size_t)l * DIM, yb);
        gemm_bt<u16><<<dim3(24, 20), 256, 0, stream>>>(yb, wtl + W1T, b1 + (size_t)l * FF, nullptr, h1b,
                                                       320, 3072, 768, 768, 3072, 1.f, 1);
        gemm_bt<float><<<dim3(6, 20), 256, 0, stream>>>(h1b, wtl + W2T, b2 + (size_t)l * DIM, t, t,
                                                        320, 768, 3072, 3072, 768, 1.f, 0);
    }
    lnf_k<<<160, 256, 0, stream>>>(t, lnf_g, lnf_b, out);
}

// Round 12
// 2078.285 us; speedup vs baseline: 1.3244x; 1.0092x over previous
//
#include <hip/hip_runtime.h>
#include <hip/hip_bf16.h>

// Sizes
#define BB 16
#define NSEQ 20
#define HEADS 8
#define DH 96
#define DIM 768
#define FF 3072
#define KMEM 32768
#define NCHUNK 4
#define CHUNK 8192
#define CAP 128

typedef unsigned short u16;
typedef __attribute__((ext_vector_type(8))) short short8v;
typedef __attribute__((ext_vector_type(4))) float f32x4;

__device__ __forceinline__ u16 f2bu(float x) {
    __hip_bfloat16 h = __float2bfloat16(x);
    return *reinterpret_cast<u16*>(&h);
}

// ---------------------------------------------------------------- weight conversion
__global__ __launch_bounds__(256) void conv_k(const float* __restrict__ src, u16* __restrict__ dst, int n)
{
    int i = blockIdx.x * 256 + threadIdx.x;
    if (i < n) dst[i] = f2bu(src[i]);
}

// transpose-convert one 32x32 tile: src[K][N] f32 -> dst[N][K] bf16 (dims % 32 == 0)
__device__ __forceinline__ void tconv_tile(const float* __restrict__ src, u16* __restrict__ dst,
                                           int K, int N, int kt, int nt, int tx, int ty)
{
    __shared__ float tile[32][33];
    int k0 = kt * 32, n0 = nt * 32;
#pragma unroll
    for (int i = 0; i < 4; i++)
        tile[ty + 8 * i][tx] = src[(size_t)(k0 + ty + 8 * i) * N + n0 + tx];
    __syncthreads();
#pragma unroll
    for (int i = 0; i < 4; i++)
        dst[(size_t)(n0 + ty + 8 * i) * K + k0 + tx] = f2bu(tile[tx][ty + 8 * i]);
}

__global__ __launch_bounds__(256) void tconv_k(const float* __restrict__ src, u16* __restrict__ dst, int K, int N)
{
    int tilesN = N >> 5;
    tconv_tile(src, dst, K, N, blockIdx.x / tilesN, blockIdx.x % tilesN,
               threadIdx.x & 31, threadIdx.x >> 5);
}

// all 5 weights of layer (blockIdx.y) in one launch; wtStride in shorts (0 => per-layer reuse)
__global__ __launch_bounds__(256) void wconv5L_k(const float* __restrict__ wq, const float* __restrict__ wkv,
    const float* __restrict__ wo, const float* __restrict__ w1, const float* __restrict__ w2,
    u16* __restrict__ wt, size_t wtStride)
{
    int l = blockIdx.y;
    wq += (size_t)l * 589824;
    wkv += (size_t)l * 147456;
    wo += (size_t)l * 589824;
    w1 += (size_t)l * 2359296;
    w2 += (size_t)l * 2359296;
    wt += (size_t)l * wtStride;
    int bx = blockIdx.x;
    int tx = threadIdx.x & 31, ty = threadIdx.x >> 5;
    if (bx < 576)       tconv_tile(wq,  wt + 0,       768, 768,  bx / 24,          bx % 24,          tx, ty);
    else if (bx < 720)  tconv_tile(wkv, wt + 589824,  768, 192,  (bx - 576) / 6,   (bx - 576) % 6,   tx, ty);
    else if (bx < 1296) tconv_tile(wo,  wt + 737280,  768, 768,  (bx - 720) / 24,  (bx - 720) % 24,  tx, ty);
    else if (bx < 3600) tconv_tile(w1,  wt + 1327104, 768, 3072, (bx - 1296) / 96, (bx - 1296) % 96, tx, ty);
    else                tconv_tile(w2,  wt + 3686400, 3072, 768, (bx - 3600) / 24, (bx - 3600) % 24, tx, ty);
}

// ---------------------------------------------------------------- MFMA GEMM, bf16 A[M][K] x Bt[N][K]
__device__ __forceinline__ void storeC(float* C, size_t idx, float v) { C[idx] = v; }
__device__ __forceinline__ void storeC(u16* C, size_t idx, float v)   { C[idx] = f2bu(v); }

template <typename CT>
__global__ __launch_bounds__(256) void gemm_bt(const u16* __restrict__ A, const u16* __restrict__ Bt,
    const float* __restrict__ bias, const float* __restrict__ resid, CT* __restrict__ C,
    int M, int N, int K, int lda, int ldc, float scale, int act)
{
    int tid = threadIdx.x;
    int w = tid >> 6, lane = tid & 63;
    int m0 = blockIdx.y * 16;
    int n0 = blockIdx.x * 128 + w * 32;
    int row = lane & 15;
    int kg  = lane >> 4;
    const u16* arow = A + (size_t)(m0 + row) * lda + kg * 8;
    int c0 = n0 + row;
    int c1 = n0 + 16 + row;
    const u16* bt0 = Bt + (size_t)min(c0, N - 1) * K + kg * 8;
    const u16* bt1 = Bt + (size_t)min(c1, N - 1) * K + kg * 8;
    f32x4 acc0 = {0.f, 0.f, 0.f, 0.f};
    f32x4 acc1 = {0.f, 0.f, 0.f, 0.f};
#pragma unroll 4
    for (int k0 = 0; k0 < K; k0 += 32) {
        short8v af = *(const short8v*)(arow + k0);
        short8v b0 = *(const short8v*)(bt0 + k0);
        short8v b1 = *(const short8v*)(bt1 + k0);
        acc0 = __builtin_amdgcn_mfma_f32_16x16x32_bf16(af, b0, acc0, 0, 0, 0);
        acc1 = __builtin_amdgcn_mfma_f32_16x16x32_bf16(af, b1, acc1, 0, 0, 0);
    }
#pragma unroll
    for (int r = 0; r < 4; r++) {
        int rw = m0 + kg * 4 + r;
        if (c0 < N) {
            float v = acc0[r] * scale;
            if (bias) v += bias[c0];
            if (act) {
                float xx = v;
                float tt = 0.7978845608028654f * (xx + 0.044715f * xx * xx * xx);
                v = 0.5f * xx * (1.0f + tanhf(tt));
            }
            if (resid) v += resid[(size_t)rw * ldc + c0];
            storeC(C, (size_t)rw * ldc + c0, v);
        }
        if (c1 < N) {
            float v = acc1[r] * scale;
            if (bias) v += bias[c1];
            if (act) {
                float xx = v;
                float tt = 0.7978845608028654f * (xx + 0.044715f * xx * xx * xx);
                v = 0.5f * xx * (1.0f + tanhf(tt));
            }
            if (resid) v += resid[(size_t)rw * ldc + c1];
            storeC(C, (size_t)rw * ldc + c1, v);
        }
    }
}

// Fused q+kv projection: Bt = [wq^T ; wkv^T] (960 rows, K=768).
// cols 0..767 -> qb (*qscale, ld 768); cols 768..959 -> kvb (ld 192).
__global__ __launch_bounds__(256) void gemm_qkv(const u16* __restrict__ A, const u16* __restrict__ Bt,
    float* __restrict__ qb, float* __restrict__ kvb, float qscale)
{
    const int N = 960, K = DIM;
    int tid = threadIdx.x;
    int w = tid >> 6, lane = tid & 63;
    int m0 = blockIdx.y * 16;
    int n0 = blockIdx.x * 128 + w * 32;
    int row = lane & 15;
    int kg  = lane >> 4;
    const u16* arow = A + (size_t)(m0 + row) * K + kg * 8;
    int c0 = n0 + row;
    int c1 = n0 + 16 + row;
    const u16* bt0 = Bt + (size_t)min(c0, N - 1) * K + kg * 8;
    const u16* bt1 = Bt + (size_t)min(c1, N - 1) * K + kg * 8;
    f32x4 acc0 = {0.f, 0.f, 0.f, 0.f};
    f32x4 acc1 = {0.f, 0.f, 0.f, 0.f};
#pragma unroll 4
    for (int k0 = 0; k0 < K; k0 += 32) {
        short8v af = *(const short8v*)(arow + k0);
        short8v b0 = *(const short8v*)(bt0 + k0);
        short8v b1 = *(const short8v*)(bt1 + k0);
        acc0 = __builtin_amdgcn_mfma_f32_16x16x32_bf16(af, b0, acc0, 0, 0, 0);
        acc1 = __builtin_amdgcn_mfma_f32_16x16x32_bf16(af, b1, acc1, 0, 0, 0);
    }
#pragma unroll
    for (int r = 0; r < 4; r++) {
        int rw = m0 + kg * 4 + r;
        if (c0 < 768)      qb[(size_t)rw * 768 + c0] = acc0[r] * qscale;
        else if (c0 < 960) kvb[(size_t)rw * 192 + (c0 - 768)] = acc0[r];
        if (c1 < 768)      qb[(size_t)rw * 768 + c1] = acc1[r] * qscale;
        else if (c1 < 960) kvb[(size_t)rw * 192 + (c1 - 768)] = acc1[r];
    }
}

// ---------------------------------------------------------------- LayerNorm (bf16 out)
__global__ __launch_bounds__(256) void ln_k(const float* __restrict__ x, const float* __restrict__ g,
    const float* __restrict__ bb, u16* __restrict__ y)
{
    int row = blockIdx.x;
    const float* xr = x + (size_t)row * DIM;
    int tid = threadIdx.x;
    float v0 = xr[tid], v1 = xr[tid + 256], v2 = xr[tid + 512];
    __shared__ float red[4];
    float s = v0 + v1 + v2;
    for (int off = 32; off; off >>= 1) s += __shfl_down(s, off);
    if ((tid & 63) == 0) red[tid >> 6] = s;
    __syncthreads();
    float mean = (red[0] + red[1] + red[2] + red[3]) * (1.f / 768.f);
    __syncthreads();
    float d0 = v0 - mean, d1 = v1 - mean, d2 = v2 - mean;
    s = d0 * d0 + d1 * d1 + d2 * d2;
    for (int off = 32; off; off >>= 1) s += __shfl_down(s, off);
    if ((tid & 63) == 0) red[tid >> 6] = s;
    __syncthreads();
    float var = (red[0] + red[1] + red[2] + red[3]) * (1.f / 768.f);
    float rs = rsqrtf(var + 1e-5f);
    u16* yr = y + (size_t)row * DIM;
    yr[tid]       = f2bu(d0 * rs * g[tid]       + bb[tid]);
    yr[tid + 256] = f2bu(d1 * rs * g[tid + 256] + bb[tid + 256]);
    yr[tid + 512] = f2bu(d2 * rs * g[tid + 512] + bb[tid + 512]);
}

// Final LN over rows i>=10, f32 output (16,10,768)
__global__ __launch_bounds__(256) void lnf_k(const float* __restrict__ x, const float* __restrict__ g,
    const float* __restrict__ bb, float* __restrict__ out)
{
    int blk = blockIdx.x;
    int b = blk / 10, ii = blk - b * 10;
    int row = b * NSEQ + 10 + ii;
    const float* xr = x + (size_t)row * DIM;
    int tid = threadIdx.x;
    float v0 = xr[tid], v1 = xr[tid + 256], v2 = xr[tid + 512];
    __shared__ float red[4];
    float s = v0 + v1 + v2;
    for (int off = 32; off; off >>= 1) s += __shfl_down(s, off);
    if ((tid & 63) == 0) red[tid >> 6] = s;
    __syncthreads();
    float mean = (red[0] + red[1] + red[2] + red[3]) * (1.f / 768.f);
    __syncthreads();
    float d0 = v0 - mean, d1 = v1 - mean, d2 = v2 - mean;
    s = d0 * d0 + d1 * d1 + d2 * d2;
    for (int off = 32; off; off >>= 1) s += __shfl_down(s, off);
    if ((tid & 63) == 0) red[tid >> 6] = s;
    __syncthreads();
    float var = (red[0] + red[1] + red[2] + red[3]) * (1.f / 768.f);
    float rs = rsqrtf(var + 1e-5f);
    float* orow = out + ((size_t)(b * 10 + ii)) * DIM;
    orow[tid]       = d0 * rs * g[tid]       + bb[tid];
    orow[tid + 256] = d1 * rs * g[tid + 256] + bb[tid + 256];
    orow[tid + 512] = d2 * rs * g[tid + 512] + bb[tid + 512];
}

// ---------------------------------------------------------------- prefix rows
__global__ __launch_bounds__(256) void prefix_k(const float* __restrict__ p, float* __restrict__ t)
{
    int idx = blockIdx.x * 256 + threadIdx.x;
    if (idx < BB * 7680) {
        int b = idx / 7680;
        int r = idx - b * 7680;
        t[(size_t)b * (NSEQ * DIM) + 7680 + r] = p[r];
    }
}

// ---------------------------------------------------------------- local attention (ao bf16)
// float4 dots in sequential accumulation order (bit-identical to scalar loop).
__device__ __forceinline__ float dot96(const float* __restrict__ a, const float* __restrict__ b)
{
    float s = 0.f;
#pragma unroll
    for (int d4 = 0; d4 < 24; d4++) {
        float4 av = *(const float4*)(a + d4 * 4);
        float4 bv = *(const float4*)(b + d4 * 4);
        s = fmaf(av.x, bv.x, s);
        s = fmaf(av.y, bv.y, s);
        s = fmaf(av.z, bv.z, s);
        s = fmaf(av.w, bv.w, s);
    }
    return s;
}

__global__ __launch_bounds__(256) void lattn_k(const float* __restrict__ q, const float* __restrict__ kv,
    u16* __restrict__ ao)
{
    int b = blockIdx.x, h = blockIdx.y;
    __shared__ float sims[NSEQ][NSEQ];
    __shared__ float probs[NSEQ][NSEQ];
    const float* qb = q + (size_t)b * NSEQ * DIM + h * DH;
    const float* kb = kv + (size_t)b * NSEQ * 192;
    int tid = threadIdx.x;
    for (int p = tid; p < NSEQ * NSEQ; p += 256) {
        int i = p / NSEQ, j = p - i * NSEQ;
        float s;
        if (j > i) s = -1.0e9f;
        else s = dot96(qb + (size_t)i * DIM, kb + j * 192);
        sims[i][j] = s;
    }
    __syncthreads();
    if (tid < NSEQ) {
        int i = tid;
        float m = -1e30f;
        for (int j = 0; j < NSEQ; j++) m = fmaxf(m, sims[i][j]);
        float sum = 0.f;
        for (int j = 0; j < NSEQ; j++) { float e = expf(sims[i][j] - m); probs[i][j] = e; sum += e; }
        float inv = 1.f / sum;
        for (int j = 0; j < NSEQ; j++) probs[i][j] *= inv;
    }
    __syncthreads();
    for (int p = tid; p < NSEQ * DH; p += 256) {
        int i = p / DH, d = p - i * DH;
        float o = 0.f;
        for (int j = 0; j <= i; j++) o = fmaf(probs[i][j], kb[j * 192 + 96 + d], o);
        ao[((size_t)b * NSEQ + i) * DIM + h * DH + d] = f2bu(o);
    }
}

// ---------------------------------------------------------------- top-k helpers
__device__ __forceinline__ bool tk_better(float va, int ia, float vb, int ib) {
    return (va > vb) || (va == vb && ia < ib);
}

__device__ __forceinline__ void lds_fence() {
    asm volatile("s_waitcnt lgkmcnt(0)" ::: "memory");
    __builtin_amdgcn_sched_barrier(0);
}

// Exact top-32 of buf[0..cnt) by (value desc, idx asc). Bitonic-128 in regs.
__device__ void topk32(float* bv, int* bi, int cnt, int lane,
                       float& ov, int& oi, float& thr_out) {
    lds_fence();
    float v0 = (lane < cnt)      ? bv[lane]      : -3.0e38f;
    int   i0 = (lane < cnt)      ? bi[lane]      : 0x7fffffff;
    float v1 = (lane + 64 < cnt) ? bv[lane + 64] : -3.0e38f;
    int   i1 = (lane + 64 < cnt) ? bi[lane + 64] : 0x7fffffff;
    lds_fence();
#pragma unroll
    for (int k = 2; k <= 128; k <<= 1) {
#pragma unroll
        for (int j = 64; j >= 1; j >>= 1) {
            if (j >= k) continue;
            if (j == 64) {
                bool asc = ((lane & k) == 0);
                bool b01 = tk_better(v0, i0, v1, i1);
                if (b01 != asc) { float tv = v0; int ti = i0; v0 = v1; i0 = i1; v1 = tv; i1 = ti; }
            } else {
                {
                    float pv = __shfl_xor(v0, j); int pi = __shfl_xor(i0, j);
                    bool asc = ((lane & k) == 0);
                    bool first = ((lane & j) == 0);
                    bool mb = tk_better(v0, i0, pv, pi);
                    bool keep = first ? (mb == asc) : (mb != asc);
                    if (!keep) { v0 = pv; i0 = pi; }
                }
                {
                    float pv = __shfl_xor(v1, j); int pi = __shfl_xor(i1, j);
                    bool asc = (((lane + 64) & k) == 0);
                    bool first = ((lane & j) == 0);
                    bool mb = tk_better(v1, i1, pv, pi);
                    bool keep = first ? (mb == asc) : (mb != asc);
                    if (!keep) { v1 = pv; i1 = pi; }
                }
            }
        }
    }
    if (lane < 32) { bv[lane] = v0; bi[lane] = i0; }
    lds_fence();
    ov = v0; oi = i0;
    thr_out = __shfl(v0, 31);
}

// One 16-key pass: dot (quarter-split), 4-lane reduce, threshold/ballot append.
__device__ __forceinline__ void tk_pass(const float4 kr[6], const float4 qreg[5][6],
    float thrR[5], int cntR[5], float (*bufv)[CAP], int (*bufi)[CAP],
    int r0, int lane, int qt, int key)
{
    float a[5];
#pragma unroll
    for (int rr = 0; rr < 5; rr++) a[rr] = 0.f;
#pragma unroll
    for (int i = 0; i < 6; i++) {
        float4 kv = kr[i];
#pragma unroll
        for (int rr = 0; rr < 5; rr++) {
            float4 qv = qreg[rr][i];
            a[rr] = fmaf(qv.x, kv.x, a[rr]);
            a[rr] = fmaf(qv.y, kv.y, a[rr]);
            a[rr] = fmaf(qv.z, kv.z, a[rr]);
            a[rr] = fmaf(qv.w, kv.w, a[rr]);
        }
    }
#pragma unroll
    for (int rr = 0; rr < 5; rr++) {
        a[rr] += __shfl_xor(a[rr], 1);
        a[rr] += __shfl_xor(a[rr], 2);
    }
#pragma unroll
    for (int rr = 0; rr < 5; rr++) {
        bool cand = (qt == 0) && (a[rr] >= thrR[rr]);
        unsigned long long mask = __ballot(cand);
        int n = __popcll(mask);
        if (n) {
            int r = r0 + rr;
            if (cntR[rr] + n > CAP) {
                float dv; int di;
                topk32(&bufv[r][0], &bufi[r][0], cntR[rr], lane, dv, di, thrR[rr]);
                cntR[rr] = 32;
            }
            int pos = cntR[rr] + __popcll(mask & ((1ull << lane) - 1ull));
            if (cand) { bufv[r][pos] = a[rr]; bufi[r][pos] = key; }
            cntR[rr] += n;
        }
    }
}

// ---------------------------------------------------------------- mem top-k v6
// Block (c,h,b), 256 thr = 4 waves; wave w owns rows 5w..5w+4. Q pinned in regs
// via amdgpu_waves_per_eu(2,2) (grid is 2 blocks/CU anyway -> 256-VGPR budget);
// 32-key double-buffered prefetch (loads issued 2 passes ahead).
// Key order, dot order, ballot order identical to v4 -> bit-identical selection.
__global__ __launch_bounds__(256) __attribute__((amdgpu_waves_per_eu(2, 2)))
void memtopk_k(const float* __restrict__ q, const float* __restrict__ memk,
    float* __restrict__ tkv, int* __restrict__ tki)
{
    __shared__ float bufv[NSEQ][CAP];
    __shared__ int   bufi[NSEQ][CAP];
    int c = blockIdx.x, h = blockIdx.y, b = blockIdx.z;
    int tid = threadIdx.x;
    int lane = tid & 63;
    int w = tid >> 6;
    int r0 = w * 5;
    int qt = lane & 3;
    int kk = lane >> 2;

    float4 qreg[5][6];
#pragma unroll
    for (int rr = 0; rr < 5; rr++) {
        const float4* qrow = (const float4*)(q + ((size_t)(b * NSEQ + r0 + rr)) * DIM + h * DH + qt * 24);
#pragma unroll
        for (int i = 0; i < 6; i++) qreg[rr][i] = qrow[i];
    }

    float thrR[5]; int cntR[5];
#pragma unroll
    for (int rr = 0; rr < 5; rr++) { thrR[rr] = -3.0e38f; cntR[rr] = 0; }

    const float* kbase = memk + (size_t)b * KMEM * DH;
    int k0 = c * CHUNK;

    // double-buffered 32-key groups: buf[0..5] = keys pass p, buf[6..11] = pass p+1
    float4 kA[12], kB[12];
#pragma unroll
    for (int s = 0; s < 2; s++) {
        const float4* kp = (const float4*)(kbase + (size_t)(k0 + s * 16 + kk) * DH + qt * 24);
#pragma unroll
        for (int i = 0; i < 6; i++) kA[s * 6 + i] = kp[i];
    }
    for (int p = 0; p < CHUNK / 16; p += 4) {
        int key0 = k0 + p * 16 + kk;
        // prefetch passes p+2, p+3 into kB (always in range: p+3 <= 511)
#pragma unroll
        for (int s = 0; s < 2; s++) {
            const float4* kp = (const float4*)(kbase + (size_t)(key0 + (32 + s * 16)) * DH + qt * 24);
#pragma unroll
            for (int i = 0; i < 6; i++) kB[s * 6 + i] = kp[i];
        }
        tk_pass(kA + 0, qreg, thrR, cntR, bufv, bufi, r0, lane, qt, key0);
        tk_pass(kA + 6, qreg, thrR, cntR, bufv, bufi, r0, lane, qt, key0 + 16);
        // prefetch passes p+4, p+5 into kA (guard tail)
        if (p + 4 < CHUNK / 16) {
#pragma unroll
            for (int s = 0; s < 2; s++) {
                const float4* kp = (const float4*)(kbase + (size_t)(key0 + (64 + s * 16)) * DH + qt * 24);
#pragma unroll
                for (int i = 0; i < 6; i++) kA[s * 6 + i] = kp[i];
            }
        }
        tk_pass(kB + 0, qreg, thrR, cntR, bufv, bufi, r0, lane, qt, key0 + 32);
        tk_pass(kB + 6, qreg, thrR, cntR, bufv, bufi, r0, lane, qt, key0 + 48);
    }
#pragma unroll
    for (int rr = 0; rr < 5; rr++) {
        int r = r0 + rr;
        float ov; int oi; float dthr;
        topk32(&bufv[r][0], &bufi[r][0], cntR[rr], lane, ov, oi, dthr);
        if (lane < 32) {
            size_t base = ((((size_t)b * HEADS + h) * NSEQ + r) * NCHUNK + c) * 32;
            tkv[base + lane] = ov;
            tki[base + lane] = oi;
        }
    }
}

// ---------------------------------------------------------------- mem attention merge (per (i,h,b))
__global__ __launch_bounds__(64) void memattn_k(const float* __restrict__ q, const float* __restrict__ kv,
    const float* __restrict__ memv, const float* __restrict__ tkv, const int* __restrict__ tki,
    u16* __restrict__ ao)
{
    int i = blockIdx.x, h = blockIdx.y, b = blockIdx.z;
    __shared__ float cv[NCHUNK * 32];
    __shared__ int   ci[NCHUNK * 32];
    __shared__ float selv[32];
    __shared__ int   seli[32];
    __shared__ float ls[NSEQ];
    __shared__ float probs[52];
    int tid = threadIdx.x;
    size_t base = (((size_t)b * HEADS + h) * NSEQ + i) * (NCHUNK * 32);
#pragma unroll
    for (int s = 0; s < NCHUNK * 32 / 64; s++) {
        cv[tid + 64 * s] = tkv[base + tid + 64 * s];
        ci[tid + 64 * s] = tki[base + tid + 64 * s];
    }
    const float* qr = q + ((size_t)b * NSEQ + i) * DIM + h * DH;
    const float* kvb = kv + (size_t)b * NSEQ * 192;
    if (tid <= i) {
        float s = dot96(qr, kvb + tid * 192);
        ls[tid] = s;
    }
    __syncthreads();
    for (int r = 0; r < 32; r++) {
        float bv = -3.0e38f; int bidx = 0x7fffffff; int bs = 0;
#pragma unroll
        for (int s = 0; s < NCHUNK * 32 / 64; s++) {
            float v = cv[tid + 64 * s]; int ix = ci[tid + 64 * s];
            if (tk_better(v, ix, bv, bidx)) { bv = v; bidx = ix; bs = tid + 64 * s; }
        }
        for (int off = 32; off; off >>= 1) {
            float ovv = __shfl_down(bv, off);
            int oii = __shfl_down(bidx, off);
            int oss = __shfl_down(bs, off);
            if (tk_better(ovv, oii, bv, bidx)) { bv = ovv; bidx = oii; bs = oss; }
        }
        if (tid == 0) { selv[r] = bv; seli[r] = bidx; cv[bs] = -3.0e38f; }
        __syncthreads();
    }
    if (tid == 0) {
        float m = -1e30f;
        for (int r = 0; r < 32; r++) m = fmaxf(m, selv[r]);
        for (int j = 0; j <= i; j++) m = fmaxf(m, ls[j]);
        float sum = 0.f;
        for (int r = 0; r < 32; r++) { float e = expf(selv[r] - m); probs[r] = e; sum += e; }
        for (int j = 0; j <= i; j++) { float e = expf(ls[j] - m); probs[32 + j] = e; sum += e; }
        float inv = 1.f / sum;
        for (int r = 0; r < 32 + i + 1; r++) probs[r] *= inv;
    }
    __syncthreads();
    const float* mvb = memv + (size_t)b * KMEM * DH;
    for (int d = tid; d < DH; d += 64) {
        float o = 0.f;
        for (int r = 0; r < 32; r++) o = fmaf(probs[r], mvb[(size_t)seli[r] * DH + d], o);
        for (int j = 0; j <= i; j++) o = fmaf(probs[32 + j], kvb[j * 192 + 96 + d], o);
        ao[((size_t)b * NSEQ + i) * DIM + h * DH + d] = f2bu(o);
    }
}

// ---------------------------------------------------------------- host
extern "C" void kernel_launch(void* const* d_in, const int* in_sizes, int n_in,
                              void* d_out, int out_size, void* d_ws, size_t ws_size,
                              hipStream_t stream) {
    const float* x            = (const float*)d_in[0];
    const float* linear_w     = (const float*)d_in[1];
    const float* linear_b     = (const float*)d_in[2];
    const float* prefix_const = (const float*)d_in[3];
    const float* ln1_g        = (const float*)d_in[4];
    const float* ln1_b        = (const float*)d_in[5];
    const float* wq           = (const float*)d_in[6];
    const float* wkv          = (const float*)d_in[7];
    const float* wo           = (const float*)d_in[8];
    const float* ln2_g        = (const float*)d_in[9];
    const float* ln2_b        = (const float*)d_in[10];
    const float* w1           = (const float*)d_in[11];
    const float* b1           = (const float*)d_in[12];
    const float* w2           = (const float*)d_in[13];
    const float* b2           = (const float*)d_in[14];
    const float* lnf_g        = (const float*)d_in[15];
    const float* lnf_b        = (const float*)d_in[16];
    const float* mem_k        = (const float*)d_in[17];
    const float* mem_v        = (const float*)d_in[18];

    float* ws = (float*)d_ws;
    float* t    = ws;                     // 320*768 f32
    u16*   yb   = (u16*)(ws + 245760);    // 320*768 bf16
    float* qb   = ws + 491520;            // 320*768 f32
    float* kvb  = ws + 737280;            // 320*192 f32
    u16*   aob  = (u16*)(ws + 798720);    // 320*768 bf16
    u16*   h1b  = (u16*)(ws + 1044480);   // 320*3072 bf16
    float* tkv  = ws + 2027520;           // 16*8*20*4*32 = 327680
    int*   tki  = (int*)(ws + 2355200);   // 327680
    u16*   wt   = (u16*)(ws + 2682880);   // weight slots (bf16)
    float* out  = (float*)d_out;

    const size_t LAYER_WT = 6045696;      // shorts per layer slot
    const int all8 = (ws_size >= (size_t)(2682880 + 8 * 3022848 + 2560) * 4) ? 1 : 0;
    u16* xb = (u16*)(ws + (all8 ? (2682880 + 8 * 3022848) : (2682880 + 3022848)));

    const float qscale = 0.10206207261596577f; // 96^-0.5
    const size_t WOT = 737280, W1T = 1327104, W2T = 3686400;

    conv_k<<<40, 256, 0, stream>>>(x, xb, 16 * 640);
    tconv_k<<<4800, 256, 0, stream>>>(linear_w, wt, 640, 7680);
    gemm_bt<float><<<dim3(60, 1), 256, 0, stream>>>(xb, wt, linear_b, nullptr, t,
                                                    16, 7680, 640, 640, 15360, 1.f, 0);
    prefix_k<<<dim3(480), 256, 0, stream>>>(prefix_const, t);

    if (all8)
        wconv5L_k<<<dim3(5904, 8), 256, 0, stream>>>(wq, wkv, wo, w1, w2, wt, LAYER_WT);

    for (int l = 0; l < 8; l++) {
        u16* wtl = wt + (all8 ? (size_t)l * LAYER_WT : 0);
        if (!all8)
            wconv5L_k<<<dim3(5904, 1), 256, 0, stream>>>(wq + (size_t)l * 589824, wkv + (size_t)l * 147456,
                                                         wo + (size_t)l * 589824, w1 + (size_t)l * 2359296,
                                                         w2 + (size_t)l * 2359296, wtl, 0);
        ln_k<<<320, 256, 0, stream>>>(t, ln1_g + (size_t)l * DIM, ln1_b + (size_t)l * DIM, yb);
        gemm_qkv<<<dim3(8, 20), 256, 0, stream>>>(yb, wtl, qb, kvb, qscale);
        if (l == 4 || l == 5) {
            memtopk_k<<<dim3(NCHUNK, HEADS, BB), 256, 0, stream>>>(qb, mem_k, tkv, tki);
            memattn_k<<<dim3(NSEQ, HEADS, BB), 64, 0, stream>>>(qb, kvb, mem_v, tkv, tki, aob);
        } else {
            lattn_k<<<dim3(BB, HEADS), 256, 0, stream>>>(qb, kvb, aob);
        }
        gemm_bt<float><<<dim3(6, 20), 256, 0, stream>>>(aob, wtl + WOT, nullptr, t, t,
                                                        320, 768, 768, 768, 768, 1.f, 0);
        ln_k<<<320, 256, 0, stream>>>(t, ln2_g + (size_t)l * DIM, ln2_b + (size_t)l * DIM, yb);
        gemm_bt<u16><<<dim3(24, 20), 256, 0, stream>>>(yb, wtl + W1T, b1 + (size_t)l * FF, nullptr, h1b,
                                                       320, 3072, 768, 768, 3072, 1.f, 1);
        gemm_bt<float><<<dim3(6, 20), 256, 0, stream>>>(h1b, wtl + W2T, b2 + (size_t)l * DIM, t, t,
                                                        320, 768, 3072, 3072, 768, 1.f, 0);
    }
    lnf_k<<<160, 256, 0, stream>>>(t, lnf_g, lnf_b, out);
}

// Round 13
// 1988.011 us; speedup vs baseline: 1.3845x; 1.0454x over previous
//
#include <hip/hip_runtime.h>
#include <hip/hip_bf16.h>

// Sizes
#define BB 16
#define NSEQ 20
#define HEADS 8
#define DH 96
#define DIM 768
#define FF 3072
#define KMEM 32768
#define NCHUNK 4
#define CHUNK 8192
#define CAP 128
#define ALDS 776   // padded LDS row (shorts): 2-way bank alias only

typedef unsigned short u16;
typedef __attribute__((ext_vector_type(8))) short short8v;
typedef __attribute__((ext_vector_type(4))) float f32x4;

__device__ __forceinline__ u16 f2bu(float x) {
    __hip_bfloat16 h = __float2bfloat16(x);
    return *reinterpret_cast<u16*>(&h);
}

// ---------------------------------------------------------------- weight conversion
__global__ __launch_bounds__(256) void conv_k(const float* __restrict__ src, u16* __restrict__ dst, int n)
{
    int i = blockIdx.x * 256 + threadIdx.x;
    if (i < n) dst[i] = f2bu(src[i]);
}

// transpose-convert one 32x32 tile: src[K][N] f32 -> dst[N][K] bf16 (dims % 32 == 0)
__device__ __forceinline__ void tconv_tile(const float* __restrict__ src, u16* __restrict__ dst,
                                           int K, int N, int kt, int nt, int tx, int ty)
{
    __shared__ float tile[32][33];
    int k0 = kt * 32, n0 = nt * 32;
#pragma unroll
    for (int i = 0; i < 4; i++)
        tile[ty + 8 * i][tx] = src[(size_t)(k0 + ty + 8 * i) * N + n0 + tx];
    __syncthreads();
#pragma unroll
    for (int i = 0; i < 4; i++)
        dst[(size_t)(n0 + ty + 8 * i) * K + k0 + tx] = f2bu(tile[tx][ty + 8 * i]);
}

__global__ __launch_bounds__(256) void tconv_k(const float* __restrict__ src, u16* __restrict__ dst, int K, int N)
{
    int tilesN = N >> 5;
    tconv_tile(src, dst, K, N, blockIdx.x / tilesN, blockIdx.x % tilesN,
               threadIdx.x & 31, threadIdx.x >> 5);
}

// all 5 weights of layer (blockIdx.y) in one launch; wtStride in shorts (0 => per-layer reuse)
__global__ __launch_bounds__(256) void wconv5L_k(const float* __restrict__ wq, const float* __restrict__ wkv,
    const float* __restrict__ wo, const float* __restrict__ w1, const float* __restrict__ w2,
    u16* __restrict__ wt, size_t wtStride)
{
    int l = blockIdx.y;
    wq += (size_t)l * 589824;
    wkv += (size_t)l * 147456;
    wo += (size_t)l * 589824;
    w1 += (size_t)l * 2359296;
    w2 += (size_t)l * 2359296;
    wt += (size_t)l * wtStride;
    int bx = blockIdx.x;
    int tx = threadIdx.x & 31, ty = threadIdx.x >> 5;
    if (bx < 576)       tconv_tile(wq,  wt + 0,       768, 768,  bx / 24,          bx % 24,          tx, ty);
    else if (bx < 720)  tconv_tile(wkv, wt + 589824,  768, 192,  (bx - 576) / 6,   (bx - 576) % 6,   tx, ty);
    else if (bx < 1296) tconv_tile(wo,  wt + 737280,  768, 768,  (bx - 720) / 24,  (bx - 720) % 24,  tx, ty);
    else if (bx < 3600) tconv_tile(w1,  wt + 1327104, 768, 3072, (bx - 1296) / 96, (bx - 1296) % 96, tx, ty);
    else                tconv_tile(w2,  wt + 3686400, 3072, 768, (bx - 3600) / 24, (bx - 3600) % 24, tx, ty);
}

// ---------------------------------------------------------------- MFMA GEMM, bf16 A[M][K] x Bt[N][K]
__device__ __forceinline__ void storeC(float* C, size_t idx, float v) { C[idx] = v; }
__device__ __forceinline__ void storeC(u16* C, size_t idx, float v)   { C[idx] = f2bu(v); }

template <typename CT>
__global__ __launch_bounds__(256) void gemm_bt(const u16* __restrict__ A, const u16* __restrict__ Bt,
    const float* __restrict__ bias, const float* __restrict__ resid, CT* __restrict__ C,
    int M, int N, int K, int lda, int ldc, float scale, int act)
{
    int tid = threadIdx.x;
    int w = tid >> 6, lane = tid & 63;
    int m0 = blockIdx.y * 16;
    int n0 = blockIdx.x * 128 + w * 32;
    int row = lane & 15;
    int kg  = lane >> 4;
    const u16* arow = A + (size_t)(m0 + row) * lda + kg * 8;
    int c0 = n0 + row;
    int c1 = n0 + 16 + row;
    const u16* bt0 = Bt + (size_t)min(c0, N - 1) * K + kg * 8;
    const u16* bt1 = Bt + (size_t)min(c1, N - 1) * K + kg * 8;
    f32x4 acc0 = {0.f, 0.f, 0.f, 0.f};
    f32x4 acc1 = {0.f, 0.f, 0.f, 0.f};
#pragma unroll 4
    for (int k0 = 0; k0 < K; k0 += 32) {
        short8v af = *(const short8v*)(arow + k0);
        short8v b0 = *(const short8v*)(bt0 + k0);
        short8v b1 = *(const short8v*)(bt1 + k0);
        acc0 = __builtin_amdgcn_mfma_f32_16x16x32_bf16(af, b0, acc0, 0, 0, 0);
        acc1 = __builtin_amdgcn_mfma_f32_16x16x32_bf16(af, b1, acc1, 0, 0, 0);
    }
#pragma unroll
    for (int r = 0; r < 4; r++) {
        int rw = m0 + kg * 4 + r;
        if (c0 < N) {
            float v = acc0[r] * scale;
            if (bias) v += bias[c0];
            if (act) {
                float xx = v;
                float tt = 0.7978845608028654f * (xx + 0.044715f * xx * xx * xx);
                v = 0.5f * xx * (1.0f + tanhf(tt));
            }
            if (resid) v += resid[(size_t)rw * ldc + c0];
            storeC(C, (size_t)rw * ldc + c0, v);
        }
        if (c1 < N) {
            float v = acc1[r] * scale;
            if (bias) v += bias[c1];
            if (act) {
                float xx = v;
                float tt = 0.7978845608028654f * (xx + 0.044715f * xx * xx * xx);
                v = 0.5f * xx * (1.0f + tanhf(tt));
            }
            if (resid) v += resid[(size_t)rw * ldc + c1];
            storeC(C, (size_t)rw * ldc + c1, v);
        }
    }
}

// ---------------------------------------------------------------- fused LN prologue (LDS A-tile)
// Computes bf16 LN of t rows [m0, m0+16) into As[16][ALDS]. 4 waves x 4 rows;
// 16 lanes per row, interleaved float4 layout (col = i*64 + sl*4).
__device__ __forceinline__ void ln_stage(const float* __restrict__ t, const float* __restrict__ g,
    const float* __restrict__ bln, int m0, int tid, u16* __restrict__ As)
{
    int lane = tid & 63, w = tid >> 6;
    int rl = w * 4 + (lane >> 4);
    int sl = lane & 15;
    const float4* tr = (const float4*)(t + (size_t)(m0 + rl) * DIM);
    float4 xv[12];
    float sum = 0.f;
#pragma unroll
    for (int i = 0; i < 12; i++) {
        xv[i] = tr[i * 16 + sl];
        sum += xv[i].x + xv[i].y + xv[i].z + xv[i].w;
    }
    sum += __shfl_xor(sum, 1); sum += __shfl_xor(sum, 2);
    sum += __shfl_xor(sum, 4); sum += __shfl_xor(sum, 8);
    float mean = sum * (1.f / 768.f);
    float vs = 0.f;
#pragma unroll
    for (int i = 0; i < 12; i++) {
        float dx = xv[i].x - mean, dy = xv[i].y - mean;
        float dz = xv[i].z - mean, dw2 = xv[i].w - mean;
        vs += dx * dx + dy * dy + dz * dz + dw2 * dw2;
    }
    vs += __shfl_xor(vs, 1); vs += __shfl_xor(vs, 2);
    vs += __shfl_xor(vs, 4); vs += __shfl_xor(vs, 8);
    float rs = rsqrtf(vs * (1.f / 768.f) + 1e-5f);
    u16* arow = As + (size_t)rl * ALDS;
#pragma unroll
    for (int i = 0; i < 12; i++) {
        int col = i * 64 + sl * 4;
        float4 gv = *(const float4*)(g + col);
        float4 bv = *(const float4*)(bln + col);
        ushort4 ov;
        ov.x = f2bu((xv[i].x - mean) * rs * gv.x + bv.x);
        ov.y = f2bu((xv[i].y - mean) * rs * gv.y + bv.y);
        ov.z = f2bu((xv[i].z - mean) * rs * gv.z + bv.z);
        ov.w = f2bu((xv[i].w - mean) * rs * gv.w + bv.w);
        *(ushort4*)(arow + col) = ov;
    }
}

// Fused LN + q/kv projection: Bt = [wq^T ; wkv^T] (960 rows, K=768).
__global__ __launch_bounds__(256) void gemm_ln_qkv(const float* __restrict__ t,
    const float* __restrict__ g, const float* __restrict__ bln, const u16* __restrict__ Bt,
    float* __restrict__ qb, float* __restrict__ kvb, float qscale)
{
    __shared__ u16 As[16 * ALDS];
    const int N = 960, K = DIM;
    int tid = threadIdx.x;
    int m0 = blockIdx.y * 16;
    ln_stage(t, g, bln, m0, tid, As);
    __syncthreads();
    int w = tid >> 6, lane = tid & 63;
    int n0 = blockIdx.x * 128 + w * 32;
    int row = lane & 15;
    int kg  = lane >> 4;
    const u16* arow = As + (size_t)row * ALDS + kg * 8;
    int c0 = n0 + row;
    int c1 = n0 + 16 + row;
    const u16* bt0 = Bt + (size_t)min(c0, N - 1) * K + kg * 8;
    const u16* bt1 = Bt + (size_t)min(c1, N - 1) * K + kg * 8;
    f32x4 acc0 = {0.f, 0.f, 0.f, 0.f};
    f32x4 acc1 = {0.f, 0.f, 0.f, 0.f};
#pragma unroll 4
    for (int k0 = 0; k0 < K; k0 += 32) {
        short8v af = *(const short8v*)(arow + k0);
        short8v b0 = *(const short8v*)(bt0 + k0);
        short8v b1 = *(const short8v*)(bt1 + k0);
        acc0 = __builtin_amdgcn_mfma_f32_16x16x32_bf16(af, b0, acc0, 0, 0, 0);
        acc1 = __builtin_amdgcn_mfma_f32_16x16x32_bf16(af, b1, acc1, 0, 0, 0);
    }
#pragma unroll
    for (int r = 0; r < 4; r++) {
        int rw = m0 + kg * 4 + r;
        if (c0 < 768)      qb[(size_t)rw * 768 + c0] = acc0[r] * qscale;
        else if (c0 < 960) kvb[(size_t)rw * 192 + (c0 - 768)] = acc0[r];
        if (c1 < 768)      qb[(size_t)rw * 768 + c1] = acc1[r] * qscale;
        else if (c1 < 960) kvb[(size_t)rw * 192 + (c1 - 768)] = acc1[r];
    }
}

// Fused LN + w1 GEMM (bias + gelu, u16 out). N=3072, K=768.
__global__ __launch_bounds__(256) void gemm_ln_w1(const float* __restrict__ t,
    const float* __restrict__ g, const float* __restrict__ bln, const u16* __restrict__ Bt,
    const float* __restrict__ bias, u16* __restrict__ C)
{
    __shared__ u16 As[16 * ALDS];
    const int N = FF, K = DIM;
    int tid = threadIdx.x;
    int m0 = blockIdx.y * 16;
    ln_stage(t, g, bln, m0, tid, As);
    __syncthreads();
    int w = tid >> 6, lane = tid & 63;
    int n0 = blockIdx.x * 128 + w * 32;
    int row = lane & 15;
    int kg  = lane >> 4;
    const u16* arow = As + (size_t)row * ALDS + kg * 8;
    int c0 = n0 + row;
    int c1 = n0 + 16 + row;
    const u16* bt0 = Bt + (size_t)c0 * K + kg * 8;
    const u16* bt1 = Bt + (size_t)c1 * K + kg * 8;
    f32x4 acc0 = {0.f, 0.f, 0.f, 0.f};
    f32x4 acc1 = {0.f, 0.f, 0.f, 0.f};
#pragma unroll 4
    for (int k0 = 0; k0 < K; k0 += 32) {
        short8v af = *(const short8v*)(arow + k0);
        short8v b0 = *(const short8v*)(bt0 + k0);
        short8v b1 = *(const short8v*)(bt1 + k0);
        acc0 = __builtin_amdgcn_mfma_f32_16x16x32_bf16(af, b0, acc0, 0, 0, 0);
        acc1 = __builtin_amdgcn_mfma_f32_16x16x32_bf16(af, b1, acc1, 0, 0, 0);
    }
#pragma unroll
    for (int r = 0; r < 4; r++) {
        int rw = m0 + kg * 4 + r;
        {
            float v = acc0[r] + bias[c0];
            float tt = 0.7978845608028654f * (v + 0.044715f * v * v * v);
            v = 0.5f * v * (1.0f + tanhf(tt));
            C[(size_t)rw * FF + c0] = f2bu(v);
        }
        {
            float v = acc1[r] + bias[c1];
            float tt = 0.7978845608028654f * (v + 0.044715f * v * v * v);
            v = 0.5f * v * (1.0f + tanhf(tt));
            C[(size_t)rw * FF + c1] = f2bu(v);
        }
    }
}

// Final LN over rows i>=10, f32 output (16,10,768)
__global__ __launch_bounds__(256) void lnf_k(const float* __restrict__ x, const float* __restrict__ g,
    const float* __restrict__ bb, float* __restrict__ out)
{
    int blk = blockIdx.x;
    int b = blk / 10, ii = blk - b * 10;
    int row = b * NSEQ + 10 + ii;
    const float* xr = x + (size_t)row * DIM;
    int tid = threadIdx.x;
    float v0 = xr[tid], v1 = xr[tid + 256], v2 = xr[tid + 512];
    __shared__ float red[4];
    float s = v0 + v1 + v2;
    for (int off = 32; off; off >>= 1) s += __shfl_down(s, off);
    if ((tid & 63) == 0) red[tid >> 6] = s;
    __syncthreads();
    float mean = (red[0] + red[1] + red[2] + red[3]) * (1.f / 768.f);
    __syncthreads();
    float d0 = v0 - mean, d1 = v1 - mean, d2 = v2 - mean;
    s = d0 * d0 + d1 * d1 + d2 * d2;
    for (int off = 32; off; off >>= 1) s += __shfl_down(s, off);
    if ((tid & 63) == 0) red[tid >> 6] = s;
    __syncthreads();
    float var = (red[0] + red[1] + red[2] + red[3]) * (1.f / 768.f);
    float rs = rsqrtf(var + 1e-5f);
    float* orow = out + ((size_t)(b * 10 + ii)) * DIM;
    orow[tid]       = d0 * rs * g[tid]       + bb[tid];
    orow[tid + 256] = d1 * rs * g[tid + 256] + bb[tid + 256];
    orow[tid + 512] = d2 * rs * g[tid + 512] + bb[tid + 512];
}

// ---------------------------------------------------------------- prefix rows
__global__ __launch_bounds__(256) void prefix_k(const float* __restrict__ p, float* __restrict__ t)
{
    int idx = blockIdx.x * 256 + threadIdx.x;
    if (idx < BB * 7680) {
        int b = idx / 7680;
        int r = idx - b * 7680;
        t[(size_t)b * (NSEQ * DIM) + 7680 + r] = p[r];
    }
}

// ---------------------------------------------------------------- local attention (ao bf16)
__device__ __forceinline__ float dot96(const float* __restrict__ a, const float* __restrict__ b)
{
    float s = 0.f;
#pragma unroll
    for (int d4 = 0; d4 < 24; d4++) {
        float4 av = *(const float4*)(a + d4 * 4);
        float4 bv = *(const float4*)(b + d4 * 4);
        s = fmaf(av.x, bv.x, s);
        s = fmaf(av.y, bv.y, s);
        s = fmaf(av.z, bv.z, s);
        s = fmaf(av.w, bv.w, s);
    }
    return s;
}

__global__ __launch_bounds__(256) void lattn_k(const float* __restrict__ q, const float* __restrict__ kv,
    u16* __restrict__ ao)
{
    int b = blockIdx.x, h = blockIdx.y;
    __shared__ float sims[NSEQ][NSEQ];
    __shared__ float probs[NSEQ][NSEQ];
    const float* qb = q + (size_t)b * NSEQ * DIM + h * DH;
    const float* kb = kv + (size_t)b * NSEQ * 192;
    int tid = threadIdx.x;
    for (int p = tid; p < NSEQ * NSEQ; p += 256) {
        int i = p / NSEQ, j = p - i * NSEQ;
        float s;
        if (j > i) s = -1.0e9f;
        else s = dot96(qb + (size_t)i * DIM, kb + j * 192);
        sims[i][j] = s;
    }
    __syncthreads();
    if (tid < NSEQ) {
        int i = tid;
        float m = -1e30f;
        for (int j = 0; j < NSEQ; j++) m = fmaxf(m, sims[i][j]);
        float sum = 0.f;
        for (int j = 0; j < NSEQ; j++) { float e = expf(sims[i][j] - m); probs[i][j] = e; sum += e; }
        float inv = 1.f / sum;
        for (int j = 0; j < NSEQ; j++) probs[i][j] *= inv;
    }
    __syncthreads();
    for (int p = tid; p < NSEQ * DH; p += 256) {
        int i = p / DH, d = p - i * DH;
        float o = 0.f;
        for (int j = 0; j <= i; j++) o = fmaf(probs[i][j], kb[j * 192 + 96 + d], o);
        ao[((size_t)b * NSEQ + i) * DIM + h * DH + d] = f2bu(o);
    }
}

// ---------------------------------------------------------------- top-k helpers
__device__ __forceinline__ bool tk_better(float va, int ia, float vb, int ib) {
    return (va > vb) || (va == vb && ia < ib);
}

__device__ __forceinline__ void lds_fence() {
    asm volatile("s_waitcnt lgkmcnt(0)" ::: "memory");
    __builtin_amdgcn_sched_barrier(0);
}

// Exact top-32 of buf[0..cnt) by (value desc, idx asc). Bitonic-128 in regs.
__device__ void topk32(float* bv, int* bi, int cnt, int lane,
                       float& ov, int& oi, float& thr_out) {
    lds_fence();
    float v0 = (lane < cnt)      ? bv[lane]      : -3.0e38f;
    int   i0 = (lane < cnt)      ? bi[lane]      : 0x7fffffff;
    float v1 = (lane + 64 < cnt) ? bv[lane + 64] : -3.0e38f;
    int   i1 = (lane + 64 < cnt) ? bi[lane + 64] : 0x7fffffff;
    lds_fence();
#pragma unroll
    for (int k = 2; k <= 128; k <<= 1) {
#pragma unroll
        for (int j = 64; j >= 1; j >>= 1) {
            if (j >= k) continue;
            if (j == 64) {
                bool asc = ((lane & k) == 0);
                bool b01 = tk_better(v0, i0, v1, i1);
                if (b01 != asc) { float tv = v0; int ti = i0; v0 = v1; i0 = i1; v1 = tv; i1 = ti; }
            } else {
                {
                    float pv = __shfl_xor(v0, j); int pi = __shfl_xor(i0, j);
                    bool asc = ((lane & k) == 0);
                    bool first = ((lane & j) == 0);
                    bool mb = tk_better(v0, i0, pv, pi);
                    bool keep = first ? (mb == asc) : (mb != asc);
                    if (!keep) { v0 = pv; i0 = pi; }
                }
                {
                    float pv = __shfl_xor(v1, j); int pi = __shfl_xor(i1, j);
                    bool asc = (((lane + 64) & k) == 0);
                    bool first = ((lane & j) == 0);
                    bool mb = tk_better(v1, i1, pv, pi);
                    bool keep = first ? (mb == asc) : (mb != asc);
                    if (!keep) { v1 = pv; i1 = pi; }
                }
            }
        }
    }
    if (lane < 32) { bv[lane] = v0; bi[lane] = i0; }
    lds_fence();
    ov = v0; oi = i0;
    thr_out = __shfl(v0, 31);
}

// One 16-key pass: dot (quarter-split), 4-lane reduce, merged-ballot append.
// Append order identical to the per-row-branch version -> bit-identical selection.
__device__ __forceinline__ void tk_pass(const float4 kr[6], const float4 qreg[5][6],
    float thrR[5], int cntR[5], float (*bufv)[CAP], int (*bufi)[CAP],
    int r0, int lane, int qt, int key)
{
    float a[5];
#pragma unroll
    for (int rr = 0; rr < 5; rr++) a[rr] = 0.f;
#pragma unroll
    for (int i = 0; i < 6; i++) {
        float4 kv = kr[i];
#pragma unroll
        for (int rr = 0; rr < 5; rr++) {
            float4 qv = qreg[rr][i];
            a[rr] = fmaf(qv.x, kv.x, a[rr]);
            a[rr] = fmaf(qv.y, kv.y, a[rr]);
            a[rr] = fmaf(qv.z, kv.z, a[rr]);
            a[rr] = fmaf(qv.w, kv.w, a[rr]);
        }
    }
#pragma unroll
    for (int rr = 0; rr < 5; rr++) {
        a[rr] += __shfl_xor(a[rr], 1);
        a[rr] += __shfl_xor(a[rr], 2);
    }
    unsigned long long m[5];
#pragma unroll
    for (int rr = 0; rr < 5; rr++) {
        bool cand = (qt == 0) && (a[rr] >= thrR[rr]);
        m[rr] = __ballot(cand);
    }
    if (m[0] | m[1] | m[2] | m[3] | m[4]) {
#pragma unroll
        for (int rr = 0; rr < 5; rr++) {
            if (m[rr]) {
                int n = __popcll(m[rr]);
                int r = r0 + rr;
                if (cntR[rr] + n > CAP) {
                    float dv; int di;
                    topk32(&bufv[r][0], &bufi[r][0], cntR[rr], lane, dv, di, thrR[rr]);
                    cntR[rr] = 32;
                }
                int pos = cntR[rr] + __popcll(m[rr] & ((1ull << lane) - 1ull));
                if ((m[rr] >> lane) & 1ull) { bufv[r][pos] = a[rr]; bufi[r][pos] = key; }
                cntR[rr] += n;
            }
        }
    }
}

// ---------------------------------------------------------------- mem top-k
// Block (c,h,b), 256 thr = 4 waves; wave w owns rows 5w..5w+4. Q in regs,
// 32-key double-buffered prefetch. 512 blocks.
__global__ __launch_bounds__(256) __attribute__((amdgpu_waves_per_eu(2, 2)))
void memtopk_k(const float* __restrict__ q, const float* __restrict__ memk,
    float* __restrict__ tkv, int* __restrict__ tki)
{
    __shared__ float bufv[NSEQ][CAP];
    __shared__ int   bufi[NSEQ][CAP];
    int c = blockIdx.x, h = blockIdx.y, b = blockIdx.z;
    int tid = threadIdx.x;
    int lane = tid & 63;
    int w = tid >> 6;
    int r0 = w * 5;
    int qt = lane & 3;
    int kk = lane >> 2;

    float4 qreg[5][6];
#pragma unroll
    for (int rr = 0; rr < 5; rr++) {
        const float4* qrow = (const float4*)(q + ((size_t)(b * NSEQ + r0 + rr)) * DIM + h * DH + qt * 24);
#pragma unroll
        for (int i = 0; i < 6; i++) qreg[rr][i] = qrow[i];
    }

    float thrR[5]; int cntR[5];
#pragma unroll
    for (int rr = 0; rr < 5; rr++) { thrR[rr] = -3.0e38f; cntR[rr] = 0; }

    const float* kbase = memk + (size_t)b * KMEM * DH;
    int k0 = c * CHUNK;

    float4 kA[12], kB[12];
#pragma unroll
    for (int s = 0; s < 2; s++) {
        const float4* kp = (const float4*)(kbase + (size_t)(k0 + s * 16 + kk) * DH + qt * 24);
#pragma unroll
        for (int i = 0; i < 6; i++) kA[s * 6 + i] = kp[i];
    }
    for (int p = 0; p < CHUNK / 16; p += 4) {
        int key0 = k0 + p * 16 + kk;
#pragma unroll
        for (int s = 0; s < 2; s++) {
            const float4* kp = (const float4*)(kbase + (size_t)(key0 + (32 + s * 16)) * DH + qt * 24);
#pragma unroll
            for (int i = 0; i < 6; i++) kB[s * 6 + i] = kp[i];
        }
        tk_pass(kA + 0, qreg, thrR, cntR, bufv, bufi, r0, lane, qt, key0);
        tk_pass(kA + 6, qreg, thrR, cntR, bufv, bufi, r0, lane, qt, key0 + 16);
        if (p + 4 < CHUNK / 16) {
#pragma unroll
            for (int s = 0; s < 2; s++) {
                const float4* kp = (const float4*)(kbase + (size_t)(key0 + (64 + s * 16)) * DH + qt * 24);
#pragma unroll
                for (int i = 0; i < 6; i++) kA[s * 6 + i] = kp[i];
            }
        }
        tk_pass(kB + 0, qreg, thrR, cntR, bufv, bufi, r0, lane, qt, key0 + 32);
        tk_pass(kB + 6, qreg, thrR, cntR, bufv, bufi, r0, lane, qt, key0 + 48);
    }
#pragma unroll
    for (int rr = 0; rr < 5; rr++) {
        int r = r0 + rr;
        float ov; int oi; float dthr;
        topk32(&bufv[r][0], &bufi[r][0], cntR[rr], lane, ov, oi, dthr);
        if (lane < 32) {
            size_t base = ((((size_t)b * HEADS + h) * NSEQ + r) * NCHUNK + c) * 32;
            tkv[base + lane] = ov;
            tki[base + lane] = oi;
        }
    }
}

// ---------------------------------------------------------------- mem attention merge (per (i,h,b))
__global__ __launch_bounds__(64) void memattn_k(const float* __restrict__ q, const float* __restrict__ kv,
    const float* __restrict__ memv, const float* __restrict__ tkv, const int* __restrict__ tki,
    u16* __restrict__ ao)
{
    int i = blockIdx.x, h = blockIdx.y, b = blockIdx.z;
    __shared__ float cv[NCHUNK * 32];
    __shared__ int   ci[NCHUNK * 32];
    __shared__ float selv[32];
    __shared__ int   seli[32];
    __shared__ float ls[NSEQ];
    __shared__ float probs[52];
    int tid = threadIdx.x;
    size_t base = (((size_t)b * HEADS + h) * NSEQ + i) * (NCHUNK * 32);
#pragma unroll
    for (int s = 0; s < NCHUNK * 32 / 64; s++) {
        cv[tid + 64 * s] = tkv[base + tid + 64 * s];
        ci[tid + 64 * s] = tki[base + tid + 64 * s];
    }
    const float* qr = q + ((size_t)b * NSEQ + i) * DIM + h * DH;
    const float* kvb = kv + (size_t)b * NSEQ * 192;
    if (tid <= i) {
        float s = dot96(qr, kvb + tid * 192);
        ls[tid] = s;
    }
    __syncthreads();
    for (int r = 0; r < 32; r++) {
        float bv = -3.0e38f; int bidx = 0x7fffffff; int bs = 0;
#pragma unroll
        for (int s = 0; s < NCHUNK * 32 / 64; s++) {
            float v = cv[tid + 64 * s]; int ix = ci[tid + 64 * s];
            if (tk_better(v, ix, bv, bidx)) { bv = v; bidx = ix; bs = tid + 64 * s; }
        }
        for (int off = 32; off; off >>= 1) {
            float ovv = __shfl_down(bv, off);
            int oii = __shfl_down(bidx, off);
            int oss = __shfl_down(bs, off);
            if (tk_better(ovv, oii, bv, bidx)) { bv = ovv; bidx = oii; bs = oss; }
        }
        if (tid == 0) { selv[r] = bv; seli[r] = bidx; cv[bs] = -3.0e38f; }
        __syncthreads();
    }
    if (tid == 0) {
        float m = -1e30f;
        for (int r = 0; r < 32; r++) m = fmaxf(m, selv[r]);
        for (int j = 0; j <= i; j++) m = fmaxf(m, ls[j]);
        float sum = 0.f;
        for (int r = 0; r < 32; r++) { float e = expf(selv[r] - m); probs[r] = e; sum += e; }
        for (int j = 0; j <= i; j++) { float e = expf(ls[j] - m); probs[32 + j] = e; sum += e; }
        float inv = 1.f / sum;
        for (int r = 0; r < 32 + i + 1; r++) probs[r] *= inv;
    }
    __syncthreads();
    const float* mvb = memv + (size_t)b * KMEM * DH;
    for (int d = tid; d < DH; d += 64) {
        float o = 0.f;
        for (int r = 0; r < 32; r++) o = fmaf(probs[r], mvb[(size_t)seli[r] * DH + d], o);
        for (int j = 0; j <= i; j++) o = fmaf(probs[32 + j], kvb[j * 192 + 96 + d], o);
        ao[((size_t)b * NSEQ + i) * DIM + h * DH + d] = f2bu(o);
    }
}

// ---------------------------------------------------------------- host
extern "C" void kernel_launch(void* const* d_in, const int* in_sizes, int n_in,
                              void* d_out, int out_size, void* d_ws, size_t ws_size,
                              hipStream_t stream) {
    const float* x            = (const float*)d_in[0];
    const float* linear_w     = (const float*)d_in[1];
    const float* linear_b     = (const float*)d_in[2];
    const float* prefix_const = (const float*)d_in[3];
    const float* ln1_g        = (const float*)d_in[4];
    const float* ln1_b        = (const float*)d_in[5];
    const float* wq           = (const float*)d_in[6];
    const float* wkv          = (const float*)d_in[7];
    const float* wo           = (const float*)d_in[8];
    const float* ln2_g        = (const float*)d_in[9];
    const float* ln2_b        = (const float*)d_in[10];
    const float* w1           = (const float*)d_in[11];
    const float* b1           = (const float*)d_in[12];
    const float* w2           = (const float*)d_in[13];
    const float* b2           = (const float*)d_in[14];
    const float* lnf_g        = (const float*)d_in[15];
    const float* lnf_b        = (const float*)d_in[16];
    const float* mem_k        = (const float*)d_in[17];
    const float* mem_v        = (const float*)d_in[18];

    float* ws = (float*)d_ws;
    float* t    = ws;                     // 320*768 f32
    u16*   yb   = (u16*)(ws + 245760);    // (unused slot, kept for layout stability)
    float* qb   = ws + 491520;            // 320*768 f32
    float* kvb  = ws + 737280;            // 320*192 f32
    u16*   aob  = (u16*)(ws + 798720);    // 320*768 bf16
    u16*   h1b  = (u16*)(ws + 1044480);   // 320*3072 bf16
    float* tkv  = ws + 2027520;           // 16*8*20*4*32 = 327680
    int*   tki  = (int*)(ws + 2355200);   // 327680
    u16*   wt   = (u16*)(ws + 2682880);   // weight slots (bf16)
    float* out  = (float*)d_out;
    (void)yb;

    const size_t LAYER_WT = 6045696;      // shorts per layer slot
    const int all8 = (ws_size >= (size_t)(2682880 + 8 * 3022848 + 2560) * 4) ? 1 : 0;
    u16* xb = (u16*)(ws + (all8 ? (2682880 + 8 * 3022848) : (2682880 + 3022848)));

    const float qscale = 0.10206207261596577f; // 96^-0.5
    const size_t WOT = 737280, W1T = 1327104, W2T = 3686400;

    conv_k<<<40, 256, 0, stream>>>(x, xb, 16 * 640);
    tconv_k<<<4800, 256, 0, stream>>>(linear_w, wt, 640, 7680);
    gemm_bt<float><<<dim3(60, 1), 256, 0, stream>>>(xb, wt, linear_b, nullptr, t,
                                                    16, 7680, 640, 640, 15360, 1.f, 0);
    prefix_k<<<dim3(480), 256, 0, stream>>>(prefix_const, t);

    if (all8)
        wconv5L_k<<<dim3(5904, 8), 256, 0, stream>>>(wq, wkv, wo, w1, w2, wt, LAYER_WT);

    for (int l = 0; l < 8; l++) {
        u16* wtl = wt + (all8 ? (size_t)l * LAYER_WT : 0);
        if (!all8)
            wconv5L_k<<<dim3(5904, 1), 256, 0, stream>>>(wq + (size_t)l * 589824, wkv + (size_t)l * 147456,
                                                         wo + (size_t)l * 589824, w1 + (size_t)l * 2359296,
                                                         w2 + (size_t)l * 2359296, wtl, 0);
        gemm_ln_qkv<<<dim3(8, 20), 256, 0, stream>>>(t, ln1_g + (size_t)l * DIM, ln1_b + (size_t)l * DIM,
                                                     wtl, qb, kvb, qscale);
        if (l == 4 || l == 5) {
            memtopk_k<<<dim3(NCHUNK, HEADS, BB), 256, 0, stream>>>(qb, mem_k, tkv, tki);
            memattn_k<<<dim3(NSEQ, HEADS, BB), 64, 0, stream>>>(qb, kvb, mem_v, tkv, tki, aob);
        } else {
            lattn_k<<<dim3(BB, HEADS), 256, 0, stream>>>(qb, kvb, aob);
        }
        gemm_bt<float><<<dim3(6, 20), 256, 0, stream>>>(aob, wtl + WOT, nullptr, t, t,
                                                        320, 768, 768, 768, 768, 1.f, 0);
        gemm_ln_w1<<<dim3(24, 20), 256, 0, stream>>>(t, ln2_g + (size_t)l * DIM, ln2_b + (size_t)l * DIM,
                                                     wtl + W1T, b1 + (size_t)l * FF, h1b);
        gemm_bt<float><<<dim3(6, 20), 256, 0, stream>>>(h1b, wtl + W2T, b2 + (size_t)l * DIM, t, t,
                                                        320, 768, 3072, 3072, 768, 1.f, 0);
    }
    lnf_k<<<160, 256, 0, stream>>>(t, lnf_g, lnf_b, out);
}

// Round 14
// 1955.914 us; speedup vs baseline: 1.4072x; 1.0164x over previous
//
#include <hip/hip_runtime.h>
#include <hip/hip_bf16.h>

// Sizes
#define BB 16
#define NSEQ 20
#define HEADS 8
#define DH 96
#define DIM 768
#define FF 3072
#define KMEM 32768
#define NCHUNK 4
#define CHUNK 8192
#define CAP 128
#define ALDS 776   // padded LDS row (shorts): 2-way bank alias only

typedef unsigned short u16;
typedef __attribute__((ext_vector_type(8))) short short8v;
typedef __attribute__((ext_vector_type(4))) float f32x4;

__device__ __forceinline__ u16 f2bu(float x) {
    __hip_bfloat16 h = __float2bfloat16(x);
    return *reinterpret_cast<u16*>(&h);
}

// ---------------------------------------------------------------- weight conversion
__global__ __launch_bounds__(256) void conv_k(const float* __restrict__ src, u16* __restrict__ dst, int n)
{
    int i = blockIdx.x * 256 + threadIdx.x;
    if (i < n) dst[i] = f2bu(src[i]);
}

// transpose-convert one 32x32 tile: src[K][N] f32 -> dst[N][K] bf16 (dims % 32 == 0)
__device__ __forceinline__ void tconv_tile(const float* __restrict__ src, u16* __restrict__ dst,
                                           int K, int N, int kt, int nt, int tx, int ty)
{
    __shared__ float tile[32][33];
    int k0 = kt * 32, n0 = nt * 32;
#pragma unroll
    for (int i = 0; i < 4; i++)
        tile[ty + 8 * i][tx] = src[(size_t)(k0 + ty + 8 * i) * N + n0 + tx];
    __syncthreads();
#pragma unroll
    for (int i = 0; i < 4; i++)
        dst[(size_t)(n0 + ty + 8 * i) * K + k0 + tx] = f2bu(tile[tx][ty + 8 * i]);
}

__global__ __launch_bounds__(256) void tconv_k(const float* __restrict__ src, u16* __restrict__ dst, int K, int N)
{
    int tilesN = N >> 5;
    tconv_tile(src, dst, K, N, blockIdx.x / tilesN, blockIdx.x % tilesN,
               threadIdx.x & 31, threadIdx.x >> 5);
}

// all 5 weights of layer (blockIdx.y) in one launch; wtStride in shorts (0 => per-layer reuse)
__global__ __launch_bounds__(256) void wconv5L_k(const float* __restrict__ wq, const float* __restrict__ wkv,
    const float* __restrict__ wo, const float* __restrict__ w1, const float* __restrict__ w2,
    u16* __restrict__ wt, size_t wtStride)
{
    int l = blockIdx.y;
    wq += (size_t)l * 589824;
    wkv += (size_t)l * 147456;
    wo += (size_t)l * 589824;
    w1 += (size_t)l * 2359296;
    w2 += (size_t)l * 2359296;
    wt += (size_t)l * wtStride;
    int bx = blockIdx.x;
    int tx = threadIdx.x & 31, ty = threadIdx.x >> 5;
    if (bx < 576)       tconv_tile(wq,  wt + 0,       768, 768,  bx / 24,          bx % 24,          tx, ty);
    else if (bx < 720)  tconv_tile(wkv, wt + 589824,  768, 192,  (bx - 576) / 6,   (bx - 576) % 6,   tx, ty);
    else if (bx < 1296) tconv_tile(wo,  wt + 737280,  768, 768,  (bx - 720) / 24,  (bx - 720) % 24,  tx, ty);
    else if (bx < 3600) tconv_tile(w1,  wt + 1327104, 768, 3072, (bx - 1296) / 96, (bx - 1296) % 96, tx, ty);
    else                tconv_tile(w2,  wt + 3686400, 3072, 768, (bx - 3600) / 24, (bx - 3600) % 24, tx, ty);
}

// ---------------------------------------------------------------- MFMA GEMM, bf16 A[M][K] x Bt[N][K]
__device__ __forceinline__ void storeC(float* C, size_t idx, float v) { C[idx] = v; }
__device__ __forceinline__ void storeC(u16* C, size_t idx, float v)   { C[idx] = f2bu(v); }

template <typename CT>
__global__ __launch_bounds__(256) void gemm_bt(const u16* __restrict__ A, const u16* __restrict__ Bt,
    const float* __restrict__ bias, const float* __restrict__ resid, CT* __restrict__ C,
    int M, int N, int K, int lda, int ldc, float scale, int act)
{
    int tid = threadIdx.x;
    int w = tid >> 6, lane = tid & 63;
    int m0 = blockIdx.y * 16;
    int n0 = blockIdx.x * 128 + w * 32;
    int row = lane & 15;
    int kg  = lane >> 4;
    const u16* arow = A + (size_t)(m0 + row) * lda + kg * 8;
    int c0 = n0 + row;
    int c1 = n0 + 16 + row;
    const u16* bt0 = Bt + (size_t)min(c0, N - 1) * K + kg * 8;
    const u16* bt1 = Bt + (size_t)min(c1, N - 1) * K + kg * 8;
    f32x4 acc0 = {0.f, 0.f, 0.f, 0.f};
    f32x4 acc1 = {0.f, 0.f, 0.f, 0.f};
#pragma unroll 4
    for (int k0 = 0; k0 < K; k0 += 32) {
        short8v af = *(const short8v*)(arow + k0);
        short8v b0 = *(const short8v*)(bt0 + k0);
        short8v b1 = *(const short8v*)(bt1 + k0);
        acc0 = __builtin_amdgcn_mfma_f32_16x16x32_bf16(af, b0, acc0, 0, 0, 0);
        acc1 = __builtin_amdgcn_mfma_f32_16x16x32_bf16(af, b1, acc1, 0, 0, 0);
    }
#pragma unroll
    for (int r = 0; r < 4; r++) {
        int rw = m0 + kg * 4 + r;
        if (c0 < N) {
            float v = acc0[r] * scale;
            if (bias) v += bias[c0];
            if (act) {
                float xx = v;
                float tt = 0.7978845608028654f * (xx + 0.044715f * xx * xx * xx);
                v = 0.5f * xx * (1.0f + tanhf(tt));
            }
            if (resid) v += resid[(size_t)rw * ldc + c0];
            storeC(C, (size_t)rw * ldc + c0, v);
        }
        if (c1 < N) {
            float v = acc1[r] * scale;
            if (bias) v += bias[c1];
            if (act) {
                float xx = v;
                float tt = 0.7978845608028654f * (xx + 0.044715f * xx * xx * xx);
                v = 0.5f * xx * (1.0f + tanhf(tt));
            }
            if (resid) v += resid[(size_t)rw * ldc + c1];
            storeC(C, (size_t)rw * ldc + c1, v);
        }
    }
}

// ---------------------------------------------------------------- fused LN prologue (LDS A-tile)
__device__ __forceinline__ void ln_stage(const float* __restrict__ t, const float* __restrict__ g,
    const float* __restrict__ bln, int m0, int tid, u16* __restrict__ As)
{
    int lane = tid & 63, w = tid >> 6;
    int rl = w * 4 + (lane >> 4);
    int sl = lane & 15;
    const float4* tr = (const float4*)(t + (size_t)(m0 + rl) * DIM);
    float4 xv[12];
    float sum = 0.f;
#pragma unroll
    for (int i = 0; i < 12; i++) {
        xv[i] = tr[i * 16 + sl];
        sum += xv[i].x + xv[i].y + xv[i].z + xv[i].w;
    }
    sum += __shfl_xor(sum, 1); sum += __shfl_xor(sum, 2);
    sum += __shfl_xor(sum, 4); sum += __shfl_xor(sum, 8);
    float mean = sum * (1.f / 768.f);
    float vs = 0.f;
#pragma unroll
    for (int i = 0; i < 12; i++) {
        float dx = xv[i].x - mean, dy = xv[i].y - mean;
        float dz = xv[i].z - mean, dw2 = xv[i].w - mean;
        vs += dx * dx + dy * dy + dz * dz + dw2 * dw2;
    }
    vs += __shfl_xor(vs, 1); vs += __shfl_xor(vs, 2);
    vs += __shfl_xor(vs, 4); vs += __shfl_xor(vs, 8);
    float rs = rsqrtf(vs * (1.f / 768.f) + 1e-5f);
    u16* arow = As + (size_t)rl * ALDS;
#pragma unroll
    for (int i = 0; i < 12; i++) {
        int col = i * 64 + sl * 4;
        float4 gv = *(const float4*)(g + col);
        float4 bv = *(const float4*)(bln + col);
        ushort4 ov;
        ov.x = f2bu((xv[i].x - mean) * rs * gv.x + bv.x);
        ov.y = f2bu((xv[i].y - mean) * rs * gv.y + bv.y);
        ov.z = f2bu((xv[i].z - mean) * rs * gv.z + bv.z);
        ov.w = f2bu((xv[i].w - mean) * rs * gv.w + bv.w);
        *(ushort4*)(arow + col) = ov;
    }
}

// Fused LN + q/kv projection: Bt = [wq^T ; wkv^T] (960 rows, K=768).
__global__ __launch_bounds__(256) void gemm_ln_qkv(const float* __restrict__ t,
    const float* __restrict__ g, const float* __restrict__ bln, const u16* __restrict__ Bt,
    float* __restrict__ qb, float* __restrict__ kvb, float qscale)
{
    __shared__ u16 As[16 * ALDS];
    const int N = 960, K = DIM;
    int tid = threadIdx.x;
    int m0 = blockIdx.y * 16;
    ln_stage(t, g, bln, m0, tid, As);
    __syncthreads();
    int w = tid >> 6, lane = tid & 63;
    int n0 = blockIdx.x * 128 + w * 32;
    int row = lane & 15;
    int kg  = lane >> 4;
    const u16* arow = As + (size_t)row * ALDS + kg * 8;
    int c0 = n0 + row;
    int c1 = n0 + 16 + row;
    const u16* bt0 = Bt + (size_t)min(c0, N - 1) * K + kg * 8;
    const u16* bt1 = Bt + (size_t)min(c1, N - 1) * K + kg * 8;
    f32x4 acc0 = {0.f, 0.f, 0.f, 0.f};
    f32x4 acc1 = {0.f, 0.f, 0.f, 0.f};
#pragma unroll 4
    for (int k0 = 0; k0 < K; k0 += 32) {
        short8v af = *(const short8v*)(arow + k0);
        short8v b0 = *(const short8v*)(bt0 + k0);
        short8v b1 = *(const short8v*)(bt1 + k0);
        acc0 = __builtin_amdgcn_mfma_f32_16x16x32_bf16(af, b0, acc0, 0, 0, 0);
        acc1 = __builtin_amdgcn_mfma_f32_16x16x32_bf16(af, b1, acc1, 0, 0, 0);
    }
#pragma unroll
    for (int r = 0; r < 4; r++) {
        int rw = m0 + kg * 4 + r;
        if (c0 < 768)      qb[(size_t)rw * 768 + c0] = acc0[r] * qscale;
        else if (c0 < 960) kvb[(size_t)rw * 192 + (c0 - 768)] = acc0[r];
        if (c1 < 768)      qb[(size_t)rw * 768 + c1] = acc1[r] * qscale;
        else if (c1 < 960) kvb[(size_t)rw * 192 + (c1 - 768)] = acc1[r];
    }
}

// Fused LN + w1 GEMM (bias + gelu, u16 out). N=3072, K=768.
__global__ __launch_bounds__(256) void gemm_ln_w1(const float* __restrict__ t,
    const float* __restrict__ g, const float* __restrict__ bln, const u16* __restrict__ Bt,
    const float* __restrict__ bias, u16* __restrict__ C)
{
    __shared__ u16 As[16 * ALDS];
    const int N = FF, K = DIM;
    int tid = threadIdx.x;
    int m0 = blockIdx.y * 16;
    ln_stage(t, g, bln, m0, tid, As);
    __syncthreads();
    int w = tid >> 6, lane = tid & 63;
    int n0 = blockIdx.x * 128 + w * 32;
    int row = lane & 15;
    int kg  = lane >> 4;
    const u16* arow = As + (size_t)row * ALDS + kg * 8;
    int c0 = n0 + row;
    int c1 = n0 + 16 + row;
    const u16* bt0 = Bt + (size_t)c0 * K + kg * 8;
    const u16* bt1 = Bt + (size_t)c1 * K + kg * 8;
    f32x4 acc0 = {0.f, 0.f, 0.f, 0.f};
    f32x4 acc1 = {0.f, 0.f, 0.f, 0.f};
#pragma unroll 4
    for (int k0 = 0; k0 < K; k0 += 32) {
        short8v af = *(const short8v*)(arow + k0);
        short8v b0 = *(const short8v*)(bt0 + k0);
        short8v b1 = *(const short8v*)(bt1 + k0);
        acc0 = __builtin_amdgcn_mfma_f32_16x16x32_bf16(af, b0, acc0, 0, 0, 0);
        acc1 = __builtin_amdgcn_mfma_f32_16x16x32_bf16(af, b1, acc1, 0, 0, 0);
    }
#pragma unroll
    for (int r = 0; r < 4; r++) {
        int rw = m0 + kg * 4 + r;
        {
            float v = acc0[r] + bias[c0];
            float tt = 0.7978845608028654f * (v + 0.044715f * v * v * v);
            v = 0.5f * v * (1.0f + tanhf(tt));
            C[(size_t)rw * FF + c0] = f2bu(v);
        }
        {
            float v = acc1[r] + bias[c1];
            float tt = 0.7978845608028654f * (v + 0.044715f * v * v * v);
            v = 0.5f * v * (1.0f + tanhf(tt));
            C[(size_t)rw * FF + c1] = f2bu(v);
        }
    }
}

// Final LN over rows i>=10, f32 output (16,10,768)
__global__ __launch_bounds__(256) void lnf_k(const float* __restrict__ x, const float* __restrict__ g,
    const float* __restrict__ bb, float* __restrict__ out)
{
    int blk = blockIdx.x;
    int b = blk / 10, ii = blk - b * 10;
    int row = b * NSEQ + 10 + ii;
    const float* xr = x + (size_t)row * DIM;
    int tid = threadIdx.x;
    float v0 = xr[tid], v1 = xr[tid + 256], v2 = xr[tid + 512];
    __shared__ float red[4];
    float s = v0 + v1 + v2;
    for (int off = 32; off; off >>= 1) s += __shfl_down(s, off);
    if ((tid & 63) == 0) red[tid >> 6] = s;
    __syncthreads();
    float mean = (red[0] + red[1] + red[2] + red[3]) * (1.f / 768.f);
    __syncthreads();
    float d0 = v0 - mean, d1 = v1 - mean, d2 = v2 - mean;
    s = d0 * d0 + d1 * d1 + d2 * d2;
    for (int off = 32; off; off >>= 1) s += __shfl_down(s, off);
    if ((tid & 63) == 0) red[tid >> 6] = s;
    __syncthreads();
    float var = (red[0] + red[1] + red[2] + red[3]) * (1.f / 768.f);
    float rs = rsqrtf(var + 1e-5f);
    float* orow = out + ((size_t)(b * 10 + ii)) * DIM;
    orow[tid]       = d0 * rs * g[tid]       + bb[tid];
    orow[tid + 256] = d1 * rs * g[tid + 256] + bb[tid + 256];
    orow[tid + 512] = d2 * rs * g[tid + 512] + bb[tid + 512];
}

// ---------------------------------------------------------------- prefix rows
__global__ __launch_bounds__(256) void prefix_k(const float* __restrict__ p, float* __restrict__ t)
{
    int idx = blockIdx.x * 256 + threadIdx.x;
    if (idx < BB * 7680) {
        int b = idx / 7680;
        int r = idx - b * 7680;
        t[(size_t)b * (NSEQ * DIM) + 7680 + r] = p[r];
    }
}

// ---------------------------------------------------------------- local attention (ao bf16)
__device__ __forceinline__ float dot96(const float* __restrict__ a, const float* __restrict__ b)
{
    float s = 0.f;
#pragma unroll
    for (int d4 = 0; d4 < 24; d4++) {
        float4 av = *(const float4*)(a + d4 * 4);
        float4 bv = *(const float4*)(b + d4 * 4);
        s = fmaf(av.x, bv.x, s);
        s = fmaf(av.y, bv.y, s);
        s = fmaf(av.z, bv.z, s);
        s = fmaf(av.w, bv.w, s);
    }
    return s;
}

__global__ __launch_bounds__(256) void lattn_k(const float* __restrict__ q, const float* __restrict__ kv,
    u16* __restrict__ ao)
{
    int b = blockIdx.x, h = blockIdx.y;
    __shared__ float sims[NSEQ][NSEQ];
    __shared__ float probs[NSEQ][NSEQ];
    const float* qb = q + (size_t)b * NSEQ * DIM + h * DH;
    const float* kb = kv + (size_t)b * NSEQ * 192;
    int tid = threadIdx.x;
    for (int p = tid; p < NSEQ * NSEQ; p += 256) {
        int i = p / NSEQ, j = p - i * NSEQ;
        float s;
        if (j > i) s = -1.0e9f;
        else s = dot96(qb + (size_t)i * DIM, kb + j * 192);
        sims[i][j] = s;
    }
    __syncthreads();
    if (tid < NSEQ) {
        int i = tid;
        float m = -1e30f;
        for (int j = 0; j < NSEQ; j++) m = fmaxf(m, sims[i][j]);
        float sum = 0.f;
        for (int j = 0; j < NSEQ; j++) { float e = expf(sims[i][j] - m); probs[i][j] = e; sum += e; }
        float inv = 1.f / sum;
        for (int j = 0; j < NSEQ; j++) probs[i][j] *= inv;
    }
    __syncthreads();
    for (int p = tid; p < NSEQ * DH; p += 256) {
        int i = p / DH, d = p - i * DH;
        float o = 0.f;
        for (int j = 0; j <= i; j++) o = fmaf(probs[i][j], kb[j * 192 + 96 + d], o);
        ao[((size_t)b * NSEQ + i) * DIM + h * DH + d] = f2bu(o);
    }
}

// ---------------------------------------------------------------- top-k helpers
__device__ __forceinline__ bool tk_better(float va, int ia, float vb, int ib) {
    return (va > vb) || (va == vb && ia < ib);
}

__device__ __forceinline__ void lds_fence() {
    asm volatile("s_waitcnt lgkmcnt(0)" ::: "memory");
    __builtin_amdgcn_sched_barrier(0);
}

// Exact top-32 of buf[0..cnt) by (value desc, idx asc). Bitonic-128 in regs.
__device__ void topk32(float* bv, int* bi, int cnt, int lane,
                       float& ov, int& oi, float& thr_out) {
    lds_fence();
    float v0 = (lane < cnt)      ? bv[lane]      : -3.0e38f;
    int   i0 = (lane < cnt)      ? bi[lane]      : 0x7fffffff;
    float v1 = (lane + 64 < cnt) ? bv[lane + 64] : -3.0e38f;
    int   i1 = (lane + 64 < cnt) ? bi[lane + 64] : 0x7fffffff;
    lds_fence();
#pragma unroll
    for (int k = 2; k <= 128; k <<= 1) {
#pragma unroll
        for (int j = 64; j >= 1; j >>= 1) {
            if (j >= k) continue;
            if (j == 64) {
                bool asc = ((lane & k) == 0);
                bool b01 = tk_better(v0, i0, v1, i1);
                if (b01 != asc) { float tv = v0; int ti = i0; v0 = v1; i0 = i1; v1 = tv; i1 = ti; }
            } else {
                {
                    float pv = __shfl_xor(v0, j); int pi = __shfl_xor(i0, j);
                    bool asc = ((lane & k) == 0);
                    bool first = ((lane & j) == 0);
                    bool mb = tk_better(v0, i0, pv, pi);
                    bool keep = first ? (mb == asc) : (mb != asc);
                    if (!keep) { v0 = pv; i0 = pi; }
                }
                {
                    float pv = __shfl_xor(v1, j); int pi = __shfl_xor(i1, j);
                    bool asc = (((lane + 64) & k) == 0);
                    bool first = ((lane & j) == 0);
                    bool mb = tk_better(v1, i1, pv, pi);
                    bool keep = first ? (mb == asc) : (mb != asc);
                    if (!keep) { v1 = pv; i1 = pi; }
                }
            }
        }
    }
    if (lane < 32) { bv[lane] = v0; bi[lane] = i0; }
    lds_fence();
    ov = v0; oi = i0;
    thr_out = __shfl(v0, 31);
}

// One 16-key pass: dot (quarter-split), 4-lane reduce, merged-ballot append.
__device__ __forceinline__ void tk_pass(const float4 kr[6], const float4 qreg[5][6],
    float thrR[5], int cntR[5], float (*bufv)[CAP], int (*bufi)[CAP],
    int r0, int lane, int qt, int key)
{
    float a[5];
#pragma unroll
    for (int rr = 0; rr < 5; rr++) a[rr] = 0.f;
#pragma unroll
    for (int i = 0; i < 6; i++) {
        float4 kv = kr[i];
#pragma unroll
        for (int rr = 0; rr < 5; rr++) {
            float4 qv = qreg[rr][i];
            a[rr] = fmaf(qv.x, kv.x, a[rr]);
            a[rr] = fmaf(qv.y, kv.y, a[rr]);
            a[rr] = fmaf(qv.z, kv.z, a[rr]);
            a[rr] = fmaf(qv.w, kv.w, a[rr]);
        }
    }
#pragma unroll
    for (int rr = 0; rr < 5; rr++) {
        a[rr] += __shfl_xor(a[rr], 1);
        a[rr] += __shfl_xor(a[rr], 2);
    }
    unsigned long long m[5];
#pragma unroll
    for (int rr = 0; rr < 5; rr++) {
        bool cand = (qt == 0) && (a[rr] >= thrR[rr]);
        m[rr] = __ballot(cand);
    }
    if (m[0] | m[1] | m[2] | m[3] | m[4]) {
#pragma unroll
        for (int rr = 0; rr < 5; rr++) {
            if (m[rr]) {
                int n = __popcll(m[rr]);
                int r = r0 + rr;
                if (cntR[rr] + n > CAP) {
                    float dv; int di;
                    topk32(&bufv[r][0], &bufi[r][0], cntR[rr], lane, dv, di, thrR[rr]);
                    cntR[rr] = 32;
                }
                int pos = cntR[rr] + __popcll(m[rr] & ((1ull << lane) - 1ull));
                if ((m[rr] >> lane) & 1ull) { bufv[r][pos] = a[rr]; bufi[r][pos] = key; }
                cntR[rr] += n;
            }
        }
    }
}

// ---------------------------------------------------------------- mem top-k
// Block (c,h,b), 256 thr = 4 waves; wave w owns rows 5w..5w+4. Q in regs,
// 32-key double-buffered prefetch. SGPR-uniform base + 32-bit byte voffset
// addressing (saddr form) — values loaded identical to v4 => bit-identical.
__global__ __launch_bounds__(256) __attribute__((amdgpu_waves_per_eu(2, 2)))
void memtopk_k(const float* __restrict__ q, const float* __restrict__ memk,
    float* __restrict__ tkv, int* __restrict__ tki)
{
    __shared__ float bufv[NSEQ][CAP];
    __shared__ int   bufi[NSEQ][CAP];
    int c = blockIdx.x, h = blockIdx.y, b = blockIdx.z;
    int tid = threadIdx.x;
    int lane = tid & 63;
    int w = tid >> 6;
    int r0 = w * 5;
    int qt = lane & 3;
    int kk = lane >> 2;

    float4 qreg[5][6];
#pragma unroll
    for (int rr = 0; rr < 5; rr++) {
        const float4* qrow = (const float4*)(q + ((size_t)(b * NSEQ + r0 + rr)) * DIM + h * DH + qt * 24);
#pragma unroll
        for (int i = 0; i < 6; i++) qreg[rr][i] = qrow[i];
    }

    float thrR[5]; int cntR[5];
#pragma unroll
    for (int rr = 0; rr < 5; rr++) { thrR[rr] = -3.0e38f; cntR[rr] = 0; }

    // block-uniform 64-bit base (SGPR), per-lane 32-bit byte offset (VGPR)
    const char* kbase = (const char*)(memk + (size_t)b * KMEM * DH);
    int k0 = c * CHUNK;
    unsigned off = ((unsigned)(k0 + kk) * 96u + (unsigned)qt * 24u) * 4u; // bytes
    const unsigned TILE = 16u * 96u * 4u;  // 6144 B per 16-key tile

    float4 kA[12], kB[12];
#pragma unroll
    for (int s = 0; s < 2; s++)
#pragma unroll
        for (int i = 0; i < 6; i++)
            kA[s * 6 + i] = *(const float4*)(kbase + (off + s * TILE + i * 16u));
    for (int p = 0; p < CHUNK / 16; p += 4) {
        int key0 = k0 + p * 16 + kk;
#pragma unroll
        for (int s = 0; s < 2; s++)
#pragma unroll
            for (int i = 0; i < 6; i++)
                kB[s * 6 + i] = *(const float4*)(kbase + (off + (2u + s) * TILE + i * 16u));
        tk_pass(kA + 0, qreg, thrR, cntR, bufv, bufi, r0, lane, qt, key0);
        tk_pass(kA + 6, qreg, thrR, cntR, bufv, bufi, r0, lane, qt, key0 + 16);
        if (p + 4 < CHUNK / 16) {
#pragma unroll
            for (int s = 0; s < 2; s++)
#pragma unroll
                for (int i = 0; i < 6; i++)
                    kA[s * 6 + i] = *(const float4*)(kbase + (off + (4u + s) * TILE + i * 16u));
        }
        tk_pass(kB + 0, qreg, thrR, cntR, bufv, bufi, r0, lane, qt, key0 + 32);
        tk_pass(kB + 6, qreg, thrR, cntR, bufv, bufi, r0, lane, qt, key0 + 48);
        off += 4u * TILE;
    }
#pragma unroll
    for (int rr = 0; rr < 5; rr++) {
        int r = r0 + rr;
        float ov; int oi; float dthr;
        topk32(&bufv[r][0], &bufi[r][0], cntR[rr], lane, ov, oi, dthr);
        if (lane < 32) {
            size_t base = ((((size_t)b * HEADS + h) * NSEQ + r) * NCHUNK + c) * 32;
            tkv[base + lane] = ov;
            tki[base + lane] = oi;
        }
    }
}

// ---------------------------------------------------------------- mem attention merge (per (i,h,b))
__global__ __launch_bounds__(64) void memattn_k(const float* __restrict__ q, const float* __restrict__ kv,
    const float* __restrict__ memv, const float* __restrict__ tkv, const int* __restrict__ tki,
    u16* __restrict__ ao)
{
    int i = blockIdx.x, h = blockIdx.y, b = blockIdx.z;
    __shared__ float cv[NCHUNK * 32];
    __shared__ int   ci[NCHUNK * 32];
    __shared__ float selv[32];
    __shared__ int   seli[32];
    __shared__ float ls[NSEQ];
    __shared__ float probs[52];
    int tid = threadIdx.x;
    size_t base = (((size_t)b * HEADS + h) * NSEQ + i) * (NCHUNK * 32);
#pragma unroll
    for (int s = 0; s < NCHUNK * 32 / 64; s++) {
        cv[tid + 64 * s] = tkv[base + tid + 64 * s];
        ci[tid + 64 * s] = tki[base + tid + 64 * s];
    }
    const float* qr = q + ((size_t)b * NSEQ + i) * DIM + h * DH;
    const float* kvb = kv + (size_t)b * NSEQ * 192;
    if (tid <= i) {
        float s = dot96(qr, kvb + tid * 192);
        ls[tid] = s;
    }
    __syncthreads();
    for (int r = 0; r < 32; r++) {
        float bv = -3.0e38f; int bidx = 0x7fffffff; int bs = 0;
#pragma unroll
        for (int s = 0; s < NCHUNK * 32 / 64; s++) {
            float v = cv[tid + 64 * s]; int ix = ci[tid + 64 * s];
            if (tk_better(v, ix, bv, bidx)) { bv = v; bidx = ix; bs = tid + 64 * s; }
        }
        for (int off = 32; off; off >>= 1) {
            float ovv = __shfl_down(bv, off);
            int oii = __shfl_down(bidx, off);
            int oss = __shfl_down(bs, off);
            if (tk_better(ovv, oii, bv, bidx)) { bv = ovv; bidx = oii; bs = oss; }
        }
        if (tid == 0) { selv[r] = bv; seli[r] = bidx; cv[bs] = -3.0e38f; }
        __syncthreads();
    }
    if (tid == 0) {
        float m = -1e30f;
        for (int r = 0; r < 32; r++) m = fmaxf(m, selv[r]);
        for (int j = 0; j <= i; j++) m = fmaxf(m, ls[j]);
        float sum = 0.f;
        for (int r = 0; r < 32; r++) { float e = expf(selv[r] - m); probs[r] = e; sum += e; }
        for (int j = 0; j <= i; j++) { float e = expf(ls[j] - m); probs[32 + j] = e; sum += e; }
        float inv = 1.f / sum;
        for (int r = 0; r < 32 + i + 1; r++) probs[r] *= inv;
    }
    __syncthreads();
    const float* mvb = memv + (size_t)b * KMEM * DH;
    for (int d = tid; d < DH; d += 64) {
        float o = 0.f;
        for (int r = 0; r < 32; r++) o = fmaf(probs[r], mvb[(size_t)seli[r] * DH + d], o);
        for (int j = 0; j <= i; j++) o = fmaf(probs[32 + j], kvb[j * 192 + 96 + d], o);
        ao[((size_t)b * NSEQ + i) * DIM + h * DH + d] = f2bu(o);
    }
}

// ---------------------------------------------------------------- host
extern "C" void kernel_launch(void* const* d_in, const int* in_sizes, int n_in,
                              void* d_out, int out_size, void* d_ws, size_t ws_size,
                              hipStream_t stream) {
    const float* x            = (const float*)d_in[0];
    const float* linear_w     = (const float*)d_in[1];
    const float* linear_b     = (const float*)d_in[2];
    const float* prefix_const = (const float*)d_in[3];
    const float* ln1_g        = (const float*)d_in[4];
    const float* ln1_b        = (const float*)d_in[5];
    const float* wq           = (const float*)d_in[6];
    const float* wkv          = (const float*)d_in[7];
    const float* wo           = (const float*)d_in[8];
    const float* ln2_g        = (const float*)d_in[9];
    const float* ln2_b        = (const float*)d_in[10];
    const float* w1           = (const float*)d_in[11];
    const float* b1           = (const float*)d_in[12];
    const float* w2           = (const float*)d_in[13];
    const float* b2           = (const float*)d_in[14];
    const float* lnf_g        = (const float*)d_in[15];
    const float* lnf_b        = (const float*)d_in[16];
    const float* mem_k        = (const float*)d_in[17];
    const float* mem_v        = (const float*)d_in[18];

    float* ws = (float*)d_ws;
    float* t    = ws;                     // 320*768 f32
    float* qb   = ws + 491520;            // 320*768 f32
    float* kvb  = ws + 737280;            // 320*192 f32
    u16*   aob  = (u16*)(ws + 798720);    // 320*768 bf16
    u16*   h1b  = (u16*)(ws + 1044480);   // 320*3072 bf16
    float* tkv  = ws + 2027520;           // 16*8*20*4*32 = 327680
    int*   tki  = (int*)(ws + 2355200);   // 327680
    u16*   wt   = (u16*)(ws + 2682880);   // weight slots (bf16)
    float* out  = (float*)d_out;

    const size_t LAYER_WT = 6045696;      // shorts per layer slot
    const int all8 = (ws_size >= (size_t)(2682880 + 8 * 3022848 + 2560) * 4) ? 1 : 0;
    u16* xb = (u16*)(ws + (all8 ? (2682880 + 8 * 3022848) : (2682880 + 3022848)));

    const float qscale = 0.10206207261596577f; // 96^-0.5
    const size_t WOT = 737280, W1T = 1327104, W2T = 3686400;

    conv_k<<<40, 256, 0, stream>>>(x, xb, 16 * 640);
    tconv_k<<<4800, 256, 0, stream>>>(linear_w, wt, 640, 7680);
    gemm_bt<float><<<dim3(60, 1), 256, 0, stream>>>(xb, wt, linear_b, nullptr, t,
                                                    16, 7680, 640, 640, 15360, 1.f, 0);
    prefix_k<<<dim3(480), 256, 0, stream>>>(prefix_const, t);

    if (all8)
        wconv5L_k<<<dim3(5904, 8), 256, 0, stream>>>(wq, wkv, wo, w1, w2, wt, LAYER_WT);

    for (int l = 0; l < 8; l++) {
        u16* wtl = wt + (all8 ? (size_t)l * LAYER_WT : 0);
        if (!all8)
            wconv5L_k<<<dim3(5904, 1), 256, 0, stream>>>(wq + (size_t)l * 589824, wkv + (size_t)l * 147456,
                                                         wo + (size_t)l * 589824, w1 + (size_t)l * 2359296,
                                                         w2 + (size_t)l * 2359296, wtl, 0);
        gemm_ln_qkv<<<dim3(8, 20), 256, 0, stream>>>(t, ln1_g + (size_t)l * DIM, ln1_b + (size_t)l * DIM,
                                                     wtl, qb, kvb, qscale);
        if (l == 4 || l == 5) {
            memtopk_k<<<dim3(NCHUNK, HEADS, BB), 256, 0, stream>>>(qb, mem_k, tkv, tki);
            memattn_k<<<dim3(NSEQ, HEADS, BB), 64, 0, stream>>>(qb, kvb, mem_v, tkv, tki, aob);
        } else {
            lattn_k<<<dim3(BB, HEADS), 256, 0, stream>>>(qb, kvb, aob);
        }
        gemm_bt<float><<<dim3(6, 20), 256, 0, stream>>>(aob, wtl + WOT, nullptr, t, t,
                                                        320, 768, 768, 768, 768, 1.f, 0);
        gemm_ln_w1<<<dim3(24, 20), 256, 0, stream>>>(t, ln2_g + (size_t)l * DIM, ln2_b + (size_t)l * DIM,
                                                     wtl + W1T, b1 + (size_t)l * FF, h1b);
        gemm_bt<float><<<dim3(6, 20), 256, 0, stream>>>(h1b, wtl + W2T, b2 + (size_t)l * DIM, t, t,
                                                        320, 768, 3072, 3072, 768, 1.f, 0);
    }
    lnf_k<<<160, 256, 0, stream>>>(t, lnf_g, lnf_b, out);
}